// Round 1
// baseline (485.989 us; speedup 1.0000x reference)
//
#include <hip/hip_runtime.h>

#define BB   32
#define NN   2048
#define DIN  128
#define DOUT 256
#define DCTX 259

// ---- workspace layout (float offsets) ----
// tt  : [0, 16777216)          fp32 [B][N][DOUT]   (aliased with M; M dead before tt written)
// M   : [0, 2097152)           fp32 [B][DOUT o][DOUT e]
#define OFF_WM  16777216u   // WMt [B][e][i]   (B*256*128)
#define OFF_K   17825792u   // k    [B][DOUT]
#define OFF_V   17833984u
#define OFF_RM  17842176u   // row max
#define OFF_RI  17850368u   // 1/row sum
#define OFF_CI  17858560u   // 1/(1e-9+col sum)
#define OFF_G   17866752u   // gate
#define OFF_HB  17874944u   // hbias
#define OFF_TB  17883136u   // tbias
#define OFF_SC  17891328u   // BN scale [N]
#define OFF_SH  17893376u   // BN shift [N]
#define OFF_WMP 17895424u   // packed WM  [B][k4][col] float4
#define OFF_WLP 18944000u   // packed W_layer [k4][col] float4
// total = 18976768 floats = 75.9 MB of ws

// K1: per-batch vectors: k, v, gate, hbias
__global__ void k1_prep(const float* __restrict__ ctx,
                        const float* __restrict__ Wk, const float* __restrict__ Wv,
                        const float* __restrict__ Wg, const float* __restrict__ bg,
                        const float* __restrict__ Whb, float* __restrict__ ws) {
    int b = blockIdx.x, t = threadIdx.x;
    __shared__ float cs[DCTX];
    for (int i = t; i < DCTX; i += 256) cs[i] = ctx[b * DCTX + i];
    __syncthreads();
    float sk = 0.f, sv = 0.f, sg = 0.f, sh = 0.f;
    const float* wk = Wk + t * 256;
    const float* wv = Wv + t * 256;
    for (int c = 0; c < 256; c++) { float cc = cs[c]; sk += cc * wk[c]; sv += cc * wv[c]; }
    const float* wg = Wg + t * DCTX;
    const float* wh = Whb + t * DCTX;
    for (int c = 0; c < DCTX; c++) { float cc = cs[c]; sg += cc * wg[c]; sh += cc * wh[c]; }
    sg += bg[t];
    ws[OFF_K  + b * DOUT + t] = sk;
    ws[OFF_V  + b * DOUT + t] = sv;
    ws[OFF_G  + b * DOUT + t] = 1.f / (1.f + __expf(-sg));
    ws[OFF_HB + b * DOUT + t] = sh;
}

// K2: per-row softmax stats (max, 1/sum) for energy[o][e] = k[o]*v[e]
__global__ void k2_rowstats(float* __restrict__ ws) {
    int b = blockIdx.x, t = threadIdx.x;
    __shared__ float vs[DOUT];
    vs[t] = ws[OFF_V + b * DOUT + t];
    __syncthreads();
    float kk = ws[OFF_K + b * DOUT + t];
    float m = -1e30f;
    for (int e = 0; e < DOUT; e++) m = fmaxf(m, kk * vs[e]);
    float s = 0.f;
    for (int e = 0; e < DOUT; e++) s += __expf(kk * vs[e] - m);
    ws[OFF_RM + b * DOUT + t] = m;
    ws[OFF_RI + b * DOUT + t] = 1.f / s;
}

// K3: column sums of row-softmaxed attention -> 1/(1e-9+colsum)
__global__ void k3_colinv(float* __restrict__ ws) {
    int b = blockIdx.x, t = threadIdx.x;
    __shared__ float ks[DOUT], rm[DOUT], ri[DOUT];
    ks[t] = ws[OFF_K + b * DOUT + t];
    rm[t] = ws[OFF_RM + b * DOUT + t];
    ri[t] = ws[OFF_RI + b * DOUT + t];
    __syncthreads();
    float ve = ws[OFF_V + b * DOUT + t];
    float s = 0.f;
    for (int o = 0; o < DOUT; o++) s += __expf(ks[o] * ve - rm[o]) * ri[o];
    ws[OFF_CI + b * DOUT + t] = 1.f / (1e-9f + s);
}

// K4: M[b][o][e] = W_tc[e][o] - sum_o' att[o][o'] * W_tc[e][o']   (att recomputed on the fly)
// grid (8 e-tiles, B), block 256 (thread = o), 32 e per block
__global__ void k4_M(const float* __restrict__ Wtc, float* __restrict__ ws) {
    int et = blockIdx.x, b = blockIdx.y, t = threadIdx.x;
    int e0 = et * 32;
    __shared__ float wt[256][33];   // wt[o'][el] = W_tc[e0+el][o']  (+1 pad: conflict-free both ways)
    __shared__ float vs[DOUT], ci[DOUT];
    for (int el = 0; el < 32; el++) wt[t][el] = Wtc[(e0 + el) * DOUT + t];
    vs[t] = ws[OFF_V + b * DOUT + t];
    ci[t] = ws[OFF_CI + b * DOUT + t];
    __syncthreads();
    float ko = ws[OFF_K + b * DOUT + t];
    float rm = ws[OFF_RM + b * DOUT + t];
    float ri = ws[OFF_RI + b * DOUT + t];
    float acc[32];
#pragma unroll
    for (int el = 0; el < 32; el++) acc[el] = wt[t][el];   // identity term
    for (int o2 = 0; o2 < DOUT; o2++) {
        float a = __expf(ko * vs[o2] - rm) * ri * ci[o2];
#pragma unroll
        for (int el = 0; el < 32; el++) acc[el] -= a * wt[o2][el];
    }
    float* Mp = ws + (unsigned)((b * DOUT + t) * DOUT + e0);
#pragma unroll
    for (int el = 0; el < 32; el++) Mp[el] = acc[el];
}

// K5: WMt[b][e][i] = sum_o W_layer[o][i] * M[b][o][e] ; tbias[b][e] = sum_o b_layer[o]*M + b_tc[e]
// grid (8 e-tiles, B), block 256: thread -> (i = t&127, eg = t>>7), 16 e each
__global__ void k5_WMt(const float* __restrict__ Wl, const float* __restrict__ bl,
                       const float* __restrict__ btc, float* __restrict__ ws) {
    int et = blockIdx.x, b = blockIdx.y, t = threadIdx.x;
    int e0 = et * 32;
    int i = t & 127, eg = t >> 7;
    __shared__ float wl[64 * 128];
    __shared__ float ml[64][33];
    __shared__ float bls[64];
    float acc[16];
#pragma unroll
    for (int j = 0; j < 16; j++) acc[j] = 0.f;
    float tb = 0.f;
    for (int ob = 0; ob < DOUT; ob += 64) {
        __syncthreads();
        for (int idx = t; idx < 64 * 128; idx += 256) wl[idx] = Wl[ob * 128 + idx];
        for (int idx = t; idx < 64 * 32; idx += 256) {
            int oo = idx >> 5, el = idx & 31;
            ml[oo][el] = ws[(unsigned)((b * DOUT + ob + oo) * DOUT + e0 + el)];
        }
        if (t < 64) bls[t] = bl[ob + t];
        __syncthreads();
        for (int oo = 0; oo < 64; oo++) {
            float w = wl[oo * 128 + i];
#pragma unroll
            for (int j = 0; j < 16; j++) acc[j] += w * ml[oo][eg * 16 + j];
        }
        if (t < 32) {
            for (int oo = 0; oo < 64; oo++) tb += bls[oo] * ml[oo][t];
        }
    }
#pragma unroll
    for (int j = 0; j < 16; j++) {
        int e = e0 + eg * 16 + j;
        ws[OFF_WM + (unsigned)((b * DOUT + e) * DIN + i)] = acc[j];
    }
    if (t < 32) ws[OFF_TB + b * DOUT + e0 + t] = tb + btc[e0 + t];
}

// K5b: pack weights k-major for coalesced GEMM loads.
// grid (32 k4, B+1): bb<B packs WM[b]; bb==B packs W_layer
__global__ void k5b_pack(const float* __restrict__ Wl, float* __restrict__ ws) {
    int k4 = blockIdx.x, bb = blockIdx.y, t = threadIdx.x;
    if (bb == BB) {
        const float* s = Wl + t * DIN + k4 * 4;
        float4 v = make_float4(s[0], s[1], s[2], s[3]);
        ((float4*)(ws + OFF_WLP))[k4 * 256 + t] = v;
    } else {
        const float* s = ws + OFF_WM + (unsigned)((bb * DOUT + t) * DIN + k4 * 4);
        float4 v = make_float4(s[0], s[1], s[2], s[3]);
        ((float4*)(ws + OFF_WMP))[(bb * 32 + k4) * 256 + t] = v;
    }
}

// K6: dual-output GEMM: x1 = x@W_layer^T + b_layer -> d_out ; tt = x@WM[b] + tbias -> ws
// grid B*64 (32 rows each), block 256 (thread = column, 2 outputs: x1 col t, tt col t)
__global__ __launch_bounds__(256) void k6_gemm(const float* __restrict__ x,
                                               const float* __restrict__ bl,
                                               float* __restrict__ out,
                                               float* __restrict__ ws) {
    int blk = blockIdx.x;
    int b = blk >> 6, nt = blk & 63;
    int n0 = nt * 32, t = threadIdx.x;
    __shared__ float4 xs[32][32];      // [row][k4], 16 KB
    const float4* xg = (const float4*)(x + (unsigned)((b * NN + n0) * DIN));
    for (int idx = t; idx < 1024; idx += 256) {
        int r = idx >> 5, k4 = idx & 31;
        xs[r][k4] = xg[r * 32 + k4];
    }
    __syncthreads();
    const float4* wap = (const float4*)(ws + OFF_WLP);            // [k4*256 + t]
    const float4* wbp = (const float4*)(ws + OFF_WMP) + b * 32 * 256;
    float acc1[32], acc2[32];
#pragma unroll
    for (int r = 0; r < 32; r++) { acc1[r] = 0.f; acc2[r] = 0.f; }
    for (int k4 = 0; k4 < 32; k4++) {
        float4 a = wap[k4 * 256 + t];
        float4 w2 = wbp[k4 * 256 + t];
#pragma unroll
        for (int r = 0; r < 32; r++) {
            float4 xv = xs[r][k4];
            acc1[r] += a.x * xv.x + a.y * xv.y + a.z * xv.z + a.w * xv.w;
            acc2[r] += w2.x * xv.x + w2.y * xv.y + w2.z * xv.z + w2.w * xv.w;
        }
    }
    float blv = bl[t];
    float tbv = ws[OFF_TB + b * DOUT + t];
#pragma unroll
    for (int r = 0; r < 32; r++) {
        unsigned row = (unsigned)(b * NN + n0 + r);
        out[row * DOUT + t] = acc1[r] + blv;
        ws[row * DOUT + t] = acc2[r] + tbv;    // tt at ws offset 0
    }
}

// K7: BN stats per n over (b,e): mean/var -> scale/shift
__global__ void k7_stats(const float* __restrict__ gamma, const float* __restrict__ beta,
                         float* __restrict__ ws) {
    int n = blockIdx.x, t = threadIdx.x;
    float s1 = 0.f, s2 = 0.f;
    for (int b = 0; b < BB; b++) {
        float v = ws[(unsigned)((b * NN + n) * DOUT + t)];
        s1 += v; s2 += v * v;
    }
    for (int off = 32; off > 0; off >>= 1) {
        s1 += __shfl_down(s1, off, 64);
        s2 += __shfl_down(s2, off, 64);
    }
    __shared__ float p1[4], p2[4];
    if ((t & 63) == 0) { p1[t >> 6] = s1; p2[t >> 6] = s2; }
    __syncthreads();
    if (t == 0) {
        float S1 = p1[0] + p1[1] + p1[2] + p1[3];
        float S2 = p2[0] + p2[1] + p2[2] + p2[3];
        float mean = S1 * (1.f / 8192.f);
        float var  = S2 * (1.f / 8192.f) - mean * mean;
        float sc = gamma[n] * rsqrtf(var + 1e-5f);
        ws[OFF_SC + n] = sc;
        ws[OFF_SH + n] = beta[n] - mean * sc;
    }
}

// K8: out = (x1 + relu(tt*scale[n]+shift[n])) * gate[b][e] + hbias[b][e], in place on d_out
__global__ void k8_final(float* __restrict__ out, const float* __restrict__ ws) {
    unsigned idx = blockIdx.x * 256u + threadIdx.x;     // float4 index, 4194304 total
    unsigned e4 = idx & 63u;
    unsigned n  = (idx >> 6) & (NN - 1u);
    unsigned b  = idx >> 17;
    float4 x1 = ((const float4*)out)[idx];
    float4 tt = ((const float4*)ws)[idx];
    float sc = ws[OFF_SC + n], sh = ws[OFF_SH + n];
    float4 g  = *(const float4*)(ws + OFF_G  + b * DOUT + (e4 << 2));
    float4 hb = *(const float4*)(ws + OFF_HB + b * DOUT + (e4 << 2));
    float4 o;
    o.x = (x1.x + fmaxf(tt.x * sc + sh, 0.f)) * g.x + hb.x;
    o.y = (x1.y + fmaxf(tt.y * sc + sh, 0.f)) * g.y + hb.y;
    o.z = (x1.z + fmaxf(tt.z * sc + sh, 0.f)) * g.z + hb.z;
    o.w = (x1.w + fmaxf(tt.w * sc + sh, 0.f)) * g.w + hb.w;
    ((float4*)out)[idx] = o;
}

extern "C" void kernel_launch(void* const* d_in, const int* in_sizes, int n_in,
                              void* d_out, int out_size, void* d_ws, size_t ws_size,
                              hipStream_t stream) {
    const float* ctx   = (const float*)d_in[0];
    const float* x     = (const float*)d_in[1];
    const float* Wl    = (const float*)d_in[2];
    const float* bl    = (const float*)d_in[3];
    const float* Whb   = (const float*)d_in[4];
    const float* Wg    = (const float*)d_in[5];
    const float* bg    = (const float*)d_in[6];
    const float* Wk    = (const float*)d_in[7];
    const float* Wv    = (const float*)d_in[8];
    const float* Wtc   = (const float*)d_in[9];
    const float* btc   = (const float*)d_in[10];
    const float* gamma = (const float*)d_in[11];
    const float* beta  = (const float*)d_in[12];
    float* out = (float*)d_out;
    float* ws  = (float*)d_ws;

    k1_prep    <<<BB, 256, 0, stream>>>(ctx, Wk, Wv, Wg, bg, Whb, ws);
    k2_rowstats<<<BB, 256, 0, stream>>>(ws);
    k3_colinv  <<<BB, 256, 0, stream>>>(ws);
    k4_M       <<<dim3(8, BB), 256, 0, stream>>>(Wtc, ws);
    k5_WMt     <<<dim3(8, BB), 256, 0, stream>>>(Wl, bl, btc, ws);
    k5b_pack   <<<dim3(32, BB + 1), 256, 0, stream>>>(Wl, ws);
    k6_gemm    <<<BB * 64, 256, 0, stream>>>(x, bl, out, ws);
    k7_stats   <<<NN, 256, 0, stream>>>(gamma, beta, ws);
    k8_final   <<<16384, 256, 0, stream>>>(out, ws);
}

// Round 3
// 422.607 us; speedup vs baseline: 1.1500x; 1.1500x over previous
//
#include <hip/hip_runtime.h>
#include <hip/hip_bf16.h>

#define BB   32
#define NN   2048
#define DIN  128
#define DOUT 256
#define DCTX 259

// ---- workspace layout (float-slot offsets) ----
// Region lifetimes: kX(XB) -> kA -> kB -> k4(M) -> k5(WM,TB) -> k5c(WLB,WMB) -> k6(TT, d_out) -> k7(SC,SH) -> k8
#define OFF_TT   0u          // tt bf16 [B][N][DOUT] = 16777216 shorts = 8388608 slots
#define OFF_M    0u          // M fp32 [B][o][e] = 2097152 slots — ALIAS: dead before k6 writes TT
#define OFF_WM   8388608u    // WMt fp32 [B][e][i] = 1048576 slots
#define OFF_XB   9437184u    // x bf16 [B][N][DIN] = 8388608 shorts = 4194304 slots
#define OFF_WLB  13631488u   // W_layer bf16 [256][128] = 16384 slots
#define OFF_WMB  13647872u   // WM bf16 [B][256][128] = 524288 slots
#define OFF_K    14172160u
#define OFF_V    14180352u
#define OFF_RM   14188544u
#define OFF_RI   14196736u
#define OFF_CI   14204928u
#define OFF_G    14213120u
#define OFF_HB   14221312u
#define OFF_TB   14229504u
#define OFF_SC   14237696u
#define OFF_SH   14239744u
// total 14241792 slots = 56.97 MB

typedef short bf16x8 __attribute__((ext_vector_type(8)));
typedef float f32x4  __attribute__((ext_vector_type(4)));

static __device__ inline unsigned short f2bf(float f) {
    __hip_bfloat16 h = __float2bfloat16(f);
    return *(unsigned short*)&h;
}
static __device__ inline float bf2f(unsigned short u) {
    unsigned v = ((unsigned)u) << 16;
    float f;
    __builtin_memcpy(&f, &v, 4);
    return f;
}

// x fp32 -> bf16 (grid 8192, 4 elems/thread)
__global__ void kX_cvt(const float* __restrict__ x, float* __restrict__ ws) {
    unsigned i = blockIdx.x * 256u + threadIdx.x;
    float4 v = ((const float4*)x)[i];
    ushort4 o;
    o.x = f2bf(v.x); o.y = f2bf(v.y); o.z = f2bf(v.z); o.w = f2bf(v.w);
    ((ushort4*)(ws + OFF_XB))[i] = o;
}

// per-batch projections k,v,gate,hbias — wave-per-row, shuffle reduce. grid (4, B)
__global__ void kA_proj(const float* __restrict__ ctx,
                        const float* __restrict__ Wk, const float* __restrict__ Wv,
                        const float* __restrict__ Wg, const float* __restrict__ bg,
                        const float* __restrict__ Whb, float* __restrict__ ws) {
    int mat = blockIdx.x, b = blockIdx.y;
    int t = threadIdx.x, wid = t >> 6, l = t & 63;
    __shared__ float cs[DCTX];
    for (int i = t; i < DCTX; i += 256) cs[i] = ctx[b * DCTX + i];
    __syncthreads();
    const float* W; int C; unsigned off;
    if (mat == 0)      { W = Wk;  C = 256;  off = OFF_K;  }
    else if (mat == 1) { W = Wv;  C = 256;  off = OFF_V;  }
    else if (mat == 2) { W = Wg;  C = DCTX; off = OFF_G;  }
    else               { W = Whb; C = DCTX; off = OFF_HB; }
    for (int r = 0; r < 64; r++) {
        int o = wid * 64 + r;
        float s = 0.f;
        for (int c = l; c < C; c += 64) s += W[o * C + c] * cs[c];
        for (int d = 32; d > 0; d >>= 1) s += __shfl_xor(s, d, 64);
        if (l == 0) {
            if (mat == 2) s = 1.f / (1.f + __expf(-(s + bg[o])));
            ws[off + b * DOUT + o] = s;
        }
    }
}

// merged softmax stats: row max, 1/rowsum, then 1/(1e-9+colsum). grid B
__global__ void kB_soft(float* __restrict__ ws) {
    int b = blockIdx.x, t = threadIdx.x;
    __shared__ float ks[DOUT], vs[DOUT], rms[DOUT], ris[DOUT];
    ks[t] = ws[OFF_K + b * DOUT + t];
    vs[t] = ws[OFF_V + b * DOUT + t];
    __syncthreads();
    float kk = ks[t];
    float m = -1e30f;
    for (int e = 0; e < DOUT; e++) m = fmaxf(m, kk * vs[e]);
    float s = 0.f;
    for (int e = 0; e < DOUT; e++) s += __expf(kk * vs[e] - m);
    float ri = 1.f / s;
    rms[t] = m; ris[t] = ri;
    ws[OFF_RM + b * DOUT + t] = m;
    ws[OFF_RI + b * DOUT + t] = ri;
    __syncthreads();
    float ve = vs[t];
    s = 0.f;
    for (int o = 0; o < DOUT; o++) s += __expf(ks[o] * ve - rms[o]) * ris[o];
    ws[OFF_CI + b * DOUT + t] = 1.f / (1e-9f + s);
}

// M[b][o][e] = W_tc[e][o] - sum_o' att[o][o'] * W_tc[e][o'].  grid (8 e-tiles, B)
__global__ void k4_M(const float* __restrict__ Wtc, float* __restrict__ ws) {
    int et = blockIdx.x, b = blockIdx.y, t = threadIdx.x;
    int e0 = et * 32;
    __shared__ float wt[256][33];
    __shared__ float vs[DOUT], ci[DOUT];
    for (int el = 0; el < 32; el++) wt[t][el] = Wtc[(e0 + el) * DOUT + t];
    vs[t] = ws[OFF_V + b * DOUT + t];
    ci[t] = ws[OFF_CI + b * DOUT + t];
    __syncthreads();
    float ko = ws[OFF_K + b * DOUT + t];
    float rm = ws[OFF_RM + b * DOUT + t];
    float ri = ws[OFF_RI + b * DOUT + t];
    float acc[32];
#pragma unroll
    for (int el = 0; el < 32; el++) acc[el] = wt[t][el];
    for (int o2 = 0; o2 < DOUT; o2++) {
        float a = __expf(ko * vs[o2] - rm) * ri * ci[o2];
#pragma unroll
        for (int el = 0; el < 32; el++) acc[el] -= a * wt[o2][el];
    }
    float* Mp = ws + OFF_M + (unsigned)((b * DOUT + t) * DOUT + e0);
#pragma unroll
    for (int el = 0; el < 32; el++) Mp[el] = acc[el];
}

// WMt[b][e][i] = sum_o W_layer[o][i]*M[b][o][e] ; tbias. grid (8, B)
__global__ void k5_WMt(const float* __restrict__ Wl, const float* __restrict__ bl,
                       const float* __restrict__ btc, float* __restrict__ ws) {
    int et = blockIdx.x, b = blockIdx.y, t = threadIdx.x;
    int e0 = et * 32;
    int i = t & 127, eg = t >> 7;
    __shared__ float wl[64 * 128];
    __shared__ float ml[64][33];
    __shared__ float bls[64];
    float acc[16];
#pragma unroll
    for (int j = 0; j < 16; j++) acc[j] = 0.f;
    float tb = 0.f;
    for (int ob = 0; ob < DOUT; ob += 64) {
        __syncthreads();
        for (int idx = t; idx < 64 * 128; idx += 256) wl[idx] = Wl[ob * 128 + idx];
        for (int idx = t; idx < 64 * 32; idx += 256) {
            int oo = idx >> 5, el = idx & 31;
            ml[oo][el] = ws[OFF_M + (unsigned)((b * DOUT + ob + oo) * DOUT + e0 + el)];
        }
        if (t < 64) bls[t] = bl[ob + t];
        __syncthreads();
        for (int oo = 0; oo < 64; oo++) {
            float w = wl[oo * 128 + i];
#pragma unroll
            for (int j = 0; j < 16; j++) acc[j] += w * ml[oo][eg * 16 + j];
        }
        if (t < 32) {
            for (int oo = 0; oo < 64; oo++) tb += bls[oo] * ml[oo][t];
        }
    }
#pragma unroll
    for (int j = 0; j < 16; j++) {
        int e = e0 + eg * 16 + j;
        ws[OFF_WM + (unsigned)((b * DOUT + e) * DIN + i)] = acc[j];
    }
    if (t < 32) ws[OFF_TB + b * DOUT + e0 + t] = tb + btc[e0 + t];
}

// pack W_layer (bb==B) and WM[b] to bf16, k-contiguous. grid B+1
__global__ void k5c_pack(const float* __restrict__ Wl, float* __restrict__ ws) {
    int bb = blockIdx.x, t = threadIdx.x;
    const float* src = (bb == BB) ? Wl : (ws + OFF_WM + (unsigned)bb * 32768u);
    unsigned short* dst = (bb == BB) ? (unsigned short*)(ws + OFF_WLB)
                                     : (unsigned short*)(ws + OFF_WMB) + (unsigned)bb * 32768u;
    for (int i = t; i < 32768; i += 256) dst[i] = f2bf(src[i]);
}

// dual GEMM via MFMA bf16: waves 0,1: x1 = xb@Wlb^T + bl -> d_out (fp32)
//                          waves 2,3: tt = xb@WMb[b] + tb -> ws TT (bf16)
// block = 32 rows x (2x128 cols x 2 outputs); wave = 32r x 128c. grid (64, B). No LDS.
__global__ __launch_bounds__(256) void k6_mfma(const float* __restrict__ bl,
                                               float* __restrict__ out,
                                               float* __restrict__ ws) {
    const int t = threadIdx.x;
    const int wid = t >> 6, l = t & 63;
    const int b = blockIdx.y;
    const int n0 = blockIdx.x * 32;
    const int lrow = l & 15, lk = l >> 4;

    const unsigned short* xb = (const unsigned short*)(ws + OFF_XB);
    const unsigned short* wb;
    int colbase;
    if (wid < 2) { wb = (const unsigned short*)(ws + OFF_WLB); colbase = wid * 128; }
    else         { wb = (const unsigned short*)(ws + OFF_WMB) + b * DOUT * DIN; colbase = (wid - 2) * 128; }

    float bias[8];
#pragma unroll
    for (int c = 0; c < 8; c++) {
        int col = colbase + c * 16 + lrow;
        bias[c] = (wid < 2) ? bl[col] : ws[OFF_TB + b * DOUT + col];
    }

    f32x4 acc[2][8];
#pragma unroll
    for (int i = 0; i < 2; i++)
#pragma unroll
        for (int c = 0; c < 8; c++) acc[i][c] = (f32x4){0.f, 0.f, 0.f, 0.f};

    const unsigned short* xr0 = xb + (size_t)((b * NN + n0 + lrow) * DIN);
#pragma unroll
    for (int kk = 0; kk < 4; kk++) {
        int ko = kk * 32 + lk * 8;
        bf16x8 a0 = *(const bf16x8*)(xr0 + ko);
        bf16x8 a1 = *(const bf16x8*)(xr0 + 16 * DIN + ko);
        bf16x8 bfr[8];
#pragma unroll
        for (int c = 0; c < 8; c++)
            bfr[c] = *(const bf16x8*)(wb + (size_t)((colbase + c * 16 + lrow) * DIN) + ko);
#pragma unroll
        for (int c = 0; c < 8; c++) {
            acc[0][c] = __builtin_amdgcn_mfma_f32_16x16x32_bf16(a0, bfr[c], acc[0][c], 0, 0, 0);
            acc[1][c] = __builtin_amdgcn_mfma_f32_16x16x32_bf16(a1, bfr[c], acc[1][c], 0, 0, 0);
        }
    }

    if (wid < 2) {
#pragma unroll
        for (int t2 = 0; t2 < 2; t2++)
#pragma unroll
            for (int c = 0; c < 8; c++)
#pragma unroll
                for (int r = 0; r < 4; r++) {
                    int row = n0 + t2 * 16 + lk * 4 + r;
                    int col = colbase + c * 16 + lrow;
                    out[(size_t)((b * NN + row) * DOUT) + col] = acc[t2][c][r] + bias[c];
                }
    } else {
        unsigned short* ttp = (unsigned short*)(ws + OFF_TT);
#pragma unroll
        for (int t2 = 0; t2 < 2; t2++)
#pragma unroll
            for (int c = 0; c < 8; c++)
#pragma unroll
                for (int r = 0; r < 4; r++) {
                    int row = n0 + t2 * 16 + lk * 4 + r;
                    int col = colbase + c * 16 + lrow;
                    ttp[(size_t)((b * NN + row) * DOUT) + col] = f2bf(acc[t2][c][r] + bias[c]);
                }
    }
}

// BN stats per n over (b,e) from bf16 tt. grid N
__global__ void k7_stats(const float* __restrict__ gamma, const float* __restrict__ beta,
                         float* __restrict__ ws) {
    int n = blockIdx.x, t = threadIdx.x;
    const unsigned short* ttb = (const unsigned short*)(ws + OFF_TT);
    float s1 = 0.f, s2 = 0.f;
    for (int b = 0; b < BB; b++) {
        float v = bf2f(ttb[(size_t)((b * NN + n) * DOUT) + t]);
        s1 += v; s2 += v * v;
    }
    for (int off = 32; off > 0; off >>= 1) {
        s1 += __shfl_down(s1, off, 64);
        s2 += __shfl_down(s2, off, 64);
    }
    __shared__ float p1[4], p2[4];
    if ((t & 63) == 0) { p1[t >> 6] = s1; p2[t >> 6] = s2; }
    __syncthreads();
    if (t == 0) {
        float S1 = p1[0] + p1[1] + p1[2] + p1[3];
        float S2 = p2[0] + p2[1] + p2[2] + p2[3];
        float mean = S1 * (1.f / 8192.f);
        float var  = S2 * (1.f / 8192.f) - mean * mean;
        float sc = gamma[n] * rsqrtf(fmaxf(var, 0.f) + 1e-5f);
        ws[OFF_SC + n] = sc;
        ws[OFF_SH + n] = beta[n] - mean * sc;
    }
}

// out = (x1 + relu(tt*sc[n]+sh[n])) * gate + hbias, in place. grid 8192, 8 elems/thread
__global__ void k8_final(float* __restrict__ out, const float* __restrict__ ws) {
    unsigned idx = blockIdx.x * 256u + threadIdx.x;    // 8-elem group
    unsigned o8 = (idx & 31u) * 8u;
    unsigned n  = (idx >> 5) & (NN - 1u);
    unsigned b  = idx >> 16;
    size_t base = (size_t)((b * NN + n) * DOUT) + o8;
    const unsigned short* ttb = (const unsigned short*)(ws + OFF_TT);
    float4 x0 = ((const float4*)(out + base))[0];
    float4 x1 = ((const float4*)(out + base))[1];
    ushort4 ta = ((const ushort4*)(ttb + base))[0];
    ushort4 tc = ((const ushort4*)(ttb + base))[1];
    float sc = ws[OFF_SC + n], sh = ws[OFF_SH + n];
    const float* gp  = ws + OFF_G  + b * DOUT + o8;
    const float* hbp = ws + OFF_HB + b * DOUT + o8;
    float4 g0 = ((const float4*)gp)[0],  g1 = ((const float4*)gp)[1];
    float4 h0 = ((const float4*)hbp)[0], h1 = ((const float4*)hbp)[1];
    float4 o0, o1;
    o0.x = (x0.x + fmaxf(bf2f(ta.x) * sc + sh, 0.f)) * g0.x + h0.x;
    o0.y = (x0.y + fmaxf(bf2f(ta.y) * sc + sh, 0.f)) * g0.y + h0.y;
    o0.z = (x0.z + fmaxf(bf2f(ta.z) * sc + sh, 0.f)) * g0.z + h0.z;
    o0.w = (x0.w + fmaxf(bf2f(ta.w) * sc + sh, 0.f)) * g0.w + h0.w;
    o1.x = (x1.x + fmaxf(bf2f(tc.x) * sc + sh, 0.f)) * g1.x + h1.x;
    o1.y = (x1.y + fmaxf(bf2f(tc.y) * sc + sh, 0.f)) * g1.y + h1.y;
    o1.z = (x1.z + fmaxf(bf2f(tc.z) * sc + sh, 0.f)) * g1.z + h1.z;
    o1.w = (x1.w + fmaxf(bf2f(tc.w) * sc + sh, 0.f)) * g1.w + h1.w;
    ((float4*)(out + base))[0] = o0;
    ((float4*)(out + base))[1] = o1;
}

extern "C" void kernel_launch(void* const* d_in, const int* in_sizes, int n_in,
                              void* d_out, int out_size, void* d_ws, size_t ws_size,
                              hipStream_t stream) {
    const float* ctx   = (const float*)d_in[0];
    const float* x     = (const float*)d_in[1];
    const float* Wl    = (const float*)d_in[2];
    const float* bl    = (const float*)d_in[3];
    const float* Whb   = (const float*)d_in[4];
    const float* Wg    = (const float*)d_in[5];
    const float* bg    = (const float*)d_in[6];
    const float* Wk    = (const float*)d_in[7];
    const float* Wv    = (const float*)d_in[8];
    const float* Wtc   = (const float*)d_in[9];
    const float* btc   = (const float*)d_in[10];
    const float* gamma = (const float*)d_in[11];
    const float* beta  = (const float*)d_in[12];
    float* out = (float*)d_out;
    float* ws  = (float*)d_ws;

    kX_cvt   <<<8192, 256, 0, stream>>>(x, ws);
    kA_proj  <<<dim3(4, BB), 256, 0, stream>>>(ctx, Wk, Wv, Wg, bg, Whb, ws);
    kB_soft  <<<BB, 256, 0, stream>>>(ws);
    k4_M     <<<dim3(8, BB), 256, 0, stream>>>(Wtc, ws);
    k5_WMt   <<<dim3(8, BB), 256, 0, stream>>>(Wl, bl, btc, ws);
    k5c_pack <<<BB + 1, 256, 0, stream>>>(Wl, ws);
    k6_mfma  <<<dim3(64, BB), 256, 0, stream>>>(bl, out, ws);
    k7_stats <<<NN, 256, 0, stream>>>(gamma, beta, ws);
    k8_final <<<8192, 256, 0, stream>>>(out, ws);
}

// Round 4
// 317.119 us; speedup vs baseline: 1.5325x; 1.3326x over previous
//
#include <hip/hip_runtime.h>
#include <hip/hip_bf16.h>

#define BB   32
#define NN   2048
#define DIN  128
#define DOUT 256
#define DCTX 259

// ---- workspace layout (float-slot offsets) ----
// TT bf16 [B][N][256] = 8388608 slots. A and Mt alias inside TT (dead before k6 writes TT).
#define OFF_TT   0u
#define OFF_AB   0u          // A  bf16 [B][256][256] = 1048576 slots, [0, 1048576)
#define OFF_MTB  1048576u    // Mt bf16 [B][256][256] = 1048576 slots, [1048576, 2097152)
#define OFF_XB   8388608u    // x bf16 [B][N][128] = 4194304 slots
#define OFF_WMB  12582912u   // WM bf16 [B][256 e][128 i] = 524288 slots
#define OFF_WLB  13107200u   // W_layer bf16 [256 o][128 i] = 16384 slots
#define OFF_WLTB 13123584u   // W_layer^T bf16 [128 i][256 o] = 16384 slots
#define OFF_WTCB 13139968u   // W_tc bf16 [256 e][256 o] = 32768 slots
#define OFF_G    13172736u
#define OFF_HB   13180928u
#define OFF_TB   13189120u
#define OFF_SC   13197312u
#define OFF_SH   13199360u
// total 13201408 slots = 52.8 MB

typedef short bf16x8 __attribute__((ext_vector_type(8)));
typedef float f32x4  __attribute__((ext_vector_type(4)));

static __device__ inline unsigned short f2bf(float f) {
    __hip_bfloat16 h = __float2bfloat16(f);
    return *(unsigned short*)&h;
}
static __device__ inline float bf2f(unsigned short u) {
    unsigned v = ((unsigned)u) << 16;
    float f;
    __builtin_memcpy(&f, &v, 4);
    return f;
}

// x fp32 -> bf16 + pack Wtc/Wl/Wl^T to bf16. grid 8202.
__global__ void kXW(const float* __restrict__ x, const float* __restrict__ Wl,
                    const float* __restrict__ Wtc, float* __restrict__ ws) {
    unsigned bb = blockIdx.x, t = threadIdx.x;
    if (bb < 8192u) {
        unsigned i = bb * 256u + t;
        float4 v = ((const float4*)x)[i];
        ushort4 o;
        o.x = f2bf(v.x); o.y = f2bf(v.y); o.z = f2bf(v.z); o.w = f2bf(v.w);
        ((ushort4*)(ws + OFF_XB))[i] = o;
    } else if (bb < 8200u) {
        unsigned base = (bb - 8192u) * 8192u;
        unsigned short* dst = (unsigned short*)(ws + OFF_WTCB);
#pragma unroll
        for (int j = 0; j < 32; j++) {
            unsigned i = base + (unsigned)j * 256u + t;
            dst[i] = f2bf(Wtc[i]);
        }
    } else if (bb == 8200u) {
        unsigned short* dst = (unsigned short*)(ws + OFF_WLTB);   // [i][o]
        for (unsigned idx = t; idx < 32768u; idx += 256u) {
            unsigned i = idx >> 8, o = idx & 255u;
            dst[idx] = f2bf(Wl[o * 128u + i]);
        }
    } else {
        unsigned short* dst = (unsigned short*)(ws + OFF_WLB);    // [o][i]
        for (unsigned idx = t; idx < 32768u; idx += 256u) dst[idx] = f2bf(Wl[idx]);
    }
}

// Fused prep: 4 GEMVs (thread-per-row, 4 independent chains) + softmax stats + A bf16. grid B.
__global__ __launch_bounds__(256) void kP(const float* __restrict__ ctx,
                                          const float* __restrict__ Wk, const float* __restrict__ Wv,
                                          const float* __restrict__ Wg, const float* __restrict__ bg,
                                          const float* __restrict__ Whb, float* __restrict__ ws) {
    int b = blockIdx.x, t = threadIdx.x;
    __shared__ float cs[DCTX + 1];
    __shared__ float ks[256], vs[256], rms[256], ris[256];
    for (int i = t; i < DCTX; i += 256) cs[i] = ctx[b * DCTX + i];
    __syncthreads();

    float sk = 0.f, sv = 0.f;
    const float4* wk4 = (const float4*)(Wk + t * 256);
    const float4* wv4 = (const float4*)(Wv + t * 256);
    const float4* cs4 = (const float4*)cs;
#pragma unroll 8
    for (int j = 0; j < 64; j++) {
        float4 c = cs4[j];
        float4 a = wk4[j];
        sk += a.x * c.x + a.y * c.y + a.z * c.z + a.w * c.w;
        float4 d = wv4[j];
        sv += d.x * c.x + d.y * c.y + d.z * c.z + d.w * c.w;
    }
    float sg = 0.f, sh = 0.f;
    const float* wg = Wg + t * DCTX;
    const float* wh = Whb + t * DCTX;
#pragma unroll 8
    for (int c = 0; c < DCTX; c++) {
        float cc = cs[c];
        sg += wg[c] * cc;
        sh += wh[c] * cc;
    }
    ws[OFF_G  + b * DOUT + t] = 1.f / (1.f + __expf(-(sg + bg[t])));
    ws[OFF_HB + b * DOUT + t] = sh;
    ks[t] = sk; vs[t] = sv;
    __syncthreads();

    // row stats (thread t = row o): max & 1/sum of exp(k_t * v_e)
    float kk = sk;
    float m = -1e30f;
    const float4* vs4 = (const float4*)vs;
#pragma unroll 4
    for (int j = 0; j < 64; j++) {
        float4 v = vs4[j];
        m = fmaxf(m, fmaxf(fmaxf(kk * v.x, kk * v.y), fmaxf(kk * v.z, kk * v.w)));
    }
    float s = 0.f;
#pragma unroll 4
    for (int j = 0; j < 64; j++) {
        float4 v = vs4[j];
        s += __expf(kk * v.x - m) + __expf(kk * v.y - m) + __expf(kk * v.z - m) + __expf(kk * v.w - m);
    }
    float ri = 1.f / s;
    rms[t] = m; ris[t] = ri;
    __syncthreads();

    // col sum (thread t = col e), then materialize A[o][t] in bf16
    float ve = sv;
    float csum = 0.f;
#pragma unroll 4
    for (int o = 0; o < 256; o++) csum += __expf(ks[o] * ve - rms[o]) * ris[o];
    float ci = 1.f / (1e-9f + csum);
    unsigned short* Ab = (unsigned short*)(ws + OFF_AB) + (size_t)b * 65536u;
#pragma unroll 4
    for (int o = 0; o < 256; o++) {
        float a = __expf(ks[o] * ve - rms[o]) * ris[o] * ci;
        Ab[o * 256 + t] = f2bf(a);
    }
}

// Mt[e][o] = Wtc[e][o] - sum_o' Wtc[e][o'] * A[o][o']  (MFMA). grid (4 e-tiles, B).
__global__ __launch_bounds__(256) void k4m(float* __restrict__ ws) {
    const int t = threadIdx.x, wid = t >> 6, l = t & 63;
    const int b = blockIdx.y, et = blockIdx.x;
    const int lrow = l & 15, lk = l >> 4;
    const int rbase = et * 64 + (wid & 1) * 32;
    const int colbase = (wid >> 1) * 128;
    const unsigned short* Wtcb = (const unsigned short*)(ws + OFF_WTCB);
    const unsigned short* Ab = (const unsigned short*)(ws + OFF_AB) + (size_t)b * 65536u;

    f32x4 acc[2][8];
#pragma unroll
    for (int i = 0; i < 2; i++)
#pragma unroll
        for (int c = 0; c < 8; c++) acc[i][c] = (f32x4){0.f, 0.f, 0.f, 0.f};

    const unsigned short* ar0 = Wtcb + (rbase + lrow) * 256;
#pragma unroll
    for (int kk = 0; kk < 8; kk++) {
        int ko = kk * 32 + lk * 8;
        bf16x8 a0 = *(const bf16x8*)(ar0 + ko);
        bf16x8 a1 = *(const bf16x8*)(ar0 + 16 * 256 + ko);
        bf16x8 bfr[8];
#pragma unroll
        for (int c = 0; c < 8; c++)
            bfr[c] = *(const bf16x8*)(Ab + (colbase + c * 16 + lrow) * 256 + ko);
#pragma unroll
        for (int c = 0; c < 8; c++) {
            acc[0][c] = __builtin_amdgcn_mfma_f32_16x16x32_bf16(a0, bfr[c], acc[0][c], 0, 0, 0);
            acc[1][c] = __builtin_amdgcn_mfma_f32_16x16x32_bf16(a1, bfr[c], acc[1][c], 0, 0, 0);
        }
    }
    unsigned short* Mtb = (unsigned short*)(ws + OFF_MTB) + (size_t)b * 65536u;
#pragma unroll
    for (int t2 = 0; t2 < 2; t2++)
#pragma unroll
        for (int c = 0; c < 8; c++)
#pragma unroll
            for (int r = 0; r < 4; r++) {
                int row = rbase + t2 * 16 + lk * 4 + r;
                int col = colbase + c * 16 + lrow;
                float idv = bf2f(Wtcb[row * 256 + col]);
                Mtb[row * 256 + col] = f2bf(idv - acc[t2][c][r]);
            }
}

// WM[e][i] = sum_o Mt[e][o] * Wl^T[i][o]  (MFMA) + tbias. grid (2 e-tiles, B).
__global__ __launch_bounds__(256) void k5m(const float* __restrict__ bl,
                                           const float* __restrict__ btc,
                                           float* __restrict__ ws) {
    const int t = threadIdx.x, wid = t >> 6, l = t & 63;
    const int b = blockIdx.y, et = blockIdx.x;
    const int lrow = l & 15, lk = l >> 4;
    const int rbase = et * 128 + wid * 32;
    const unsigned short* Mtb = (const unsigned short*)(ws + OFF_MTB) + (size_t)b * 65536u;
    const unsigned short* Wltb = (const unsigned short*)(ws + OFF_WLTB);

    f32x4 acc[2][8];
#pragma unroll
    for (int i = 0; i < 2; i++)
#pragma unroll
        for (int c = 0; c < 8; c++) acc[i][c] = (f32x4){0.f, 0.f, 0.f, 0.f};

    const unsigned short* ar0 = Mtb + (rbase + lrow) * 256;
#pragma unroll
    for (int kk = 0; kk < 8; kk++) {
        int ko = kk * 32 + lk * 8;
        bf16x8 a0 = *(const bf16x8*)(ar0 + ko);
        bf16x8 a1 = *(const bf16x8*)(ar0 + 16 * 256 + ko);
        bf16x8 bfr[8];
#pragma unroll
        for (int c = 0; c < 8; c++)
            bfr[c] = *(const bf16x8*)(Wltb + (c * 16 + lrow) * 256 + ko);
#pragma unroll
        for (int c = 0; c < 8; c++) {
            acc[0][c] = __builtin_amdgcn_mfma_f32_16x16x32_bf16(a0, bfr[c], acc[0][c], 0, 0, 0);
            acc[1][c] = __builtin_amdgcn_mfma_f32_16x16x32_bf16(a1, bfr[c], acc[1][c], 0, 0, 0);
        }
    }
    unsigned short* WMBp = (unsigned short*)(ws + OFF_WMB) + (size_t)b * 32768u;
#pragma unroll
    for (int t2 = 0; t2 < 2; t2++)
#pragma unroll
        for (int c = 0; c < 8; c++)
#pragma unroll
            for (int r = 0; r < 4; r++) {
                int row = rbase + t2 * 16 + lk * 4 + r;   // e
                int col = c * 16 + lrow;                  // i
                WMBp[row * 128 + col] = f2bf(acc[t2][c][r]);
            }
    // tbias[e] = sum_o bl[o] * Mt[e][o] + btc[e]
    if (t < 128) {
        int e = et * 128 + t;
        const unsigned short* mrow = Mtb + e * 256;
        float s = 0.f;
#pragma unroll 8
        for (int o = 0; o < 256; o++) s += bl[o] * bf2f(mrow[o]);
        ws[OFF_TB + b * DOUT + e] = s + btc[e];
    }
}

// dual GEMM via MFMA bf16: waves 0,1: x1 = xb@Wlb^T + bl -> d_out (fp32)
//                          waves 2,3: tt = xb@WMb[b] + tb -> ws TT (bf16)
// block = 32 rows; wave = 32r x 128c. grid (64, B). No LDS.
__global__ __launch_bounds__(256) void k6_mfma(const float* __restrict__ bl,
                                               float* __restrict__ out,
                                               float* __restrict__ ws) {
    const int t = threadIdx.x;
    const int wid = t >> 6, l = t & 63;
    const int b = blockIdx.y;
    const int n0 = blockIdx.x * 32;
    const int lrow = l & 15, lk = l >> 4;

    const unsigned short* xb = (const unsigned short*)(ws + OFF_XB);
    const unsigned short* wb;
    int colbase;
    if (wid < 2) { wb = (const unsigned short*)(ws + OFF_WLB); colbase = wid * 128; }
    else         { wb = (const unsigned short*)(ws + OFF_WMB) + (size_t)b * DOUT * DIN; colbase = (wid - 2) * 128; }

    float bias[8];
#pragma unroll
    for (int c = 0; c < 8; c++) {
        int col = colbase + c * 16 + lrow;
        bias[c] = (wid < 2) ? bl[col] : ws[OFF_TB + b * DOUT + col];
    }

    f32x4 acc[2][8];
#pragma unroll
    for (int i = 0; i < 2; i++)
#pragma unroll
        for (int c = 0; c < 8; c++) acc[i][c] = (f32x4){0.f, 0.f, 0.f, 0.f};

    const unsigned short* xr0 = xb + (size_t)((b * NN + n0 + lrow) * DIN);
#pragma unroll
    for (int kk = 0; kk < 4; kk++) {
        int ko = kk * 32 + lk * 8;
        bf16x8 a0 = *(const bf16x8*)(xr0 + ko);
        bf16x8 a1 = *(const bf16x8*)(xr0 + 16 * DIN + ko);
        bf16x8 bfr[8];
#pragma unroll
        for (int c = 0; c < 8; c++)
            bfr[c] = *(const bf16x8*)(wb + (size_t)((colbase + c * 16 + lrow) * DIN) + ko);
#pragma unroll
        for (int c = 0; c < 8; c++) {
            acc[0][c] = __builtin_amdgcn_mfma_f32_16x16x32_bf16(a0, bfr[c], acc[0][c], 0, 0, 0);
            acc[1][c] = __builtin_amdgcn_mfma_f32_16x16x32_bf16(a1, bfr[c], acc[1][c], 0, 0, 0);
        }
    }

    if (wid < 2) {
#pragma unroll
        for (int t2 = 0; t2 < 2; t2++)
#pragma unroll
            for (int c = 0; c < 8; c++)
#pragma unroll
                for (int r = 0; r < 4; r++) {
                    int row = n0 + t2 * 16 + lk * 4 + r;
                    int col = colbase + c * 16 + lrow;
                    out[(size_t)((b * NN + row) * DOUT) + col] = acc[t2][c][r] + bias[c];
                }
    } else {
        unsigned short* ttp = (unsigned short*)(ws + OFF_TT);
#pragma unroll
        for (int t2 = 0; t2 < 2; t2++)
#pragma unroll
            for (int c = 0; c < 8; c++)
#pragma unroll
                for (int r = 0; r < 4; r++) {
                    int row = n0 + t2 * 16 + lk * 4 + r;
                    int col = colbase + c * 16 + lrow;
                    ttp[(size_t)((b * NN + row) * DOUT) + col] = f2bf(acc[t2][c][r] + bias[c]);
                }
    }
}

// BN stats per n over (b,e) from bf16 tt. grid N
__global__ void k7_stats(const float* __restrict__ gamma, const float* __restrict__ beta,
                         float* __restrict__ ws) {
    int n = blockIdx.x, t = threadIdx.x;
    const unsigned short* ttb = (const unsigned short*)(ws + OFF_TT);
    float s1 = 0.f, s2 = 0.f;
    for (int b = 0; b < BB; b++) {
        float v = bf2f(ttb[(size_t)((b * NN + n) * DOUT) + t]);
        s1 += v; s2 += v * v;
    }
    for (int off = 32; off > 0; off >>= 1) {
        s1 += __shfl_down(s1, off, 64);
        s2 += __shfl_down(s2, off, 64);
    }
    __shared__ float p1[4], p2[4];
    if ((t & 63) == 0) { p1[t >> 6] = s1; p2[t >> 6] = s2; }
    __syncthreads();
    if (t == 0) {
        float S1 = p1[0] + p1[1] + p1[2] + p1[3];
        float S2 = p2[0] + p2[1] + p2[2] + p2[3];
        float mean = S1 * (1.f / 8192.f);
        float var  = S2 * (1.f / 8192.f) - mean * mean;
        float sc = gamma[n] * rsqrtf(fmaxf(var, 0.f) + 1e-5f);
        ws[OFF_SC + n] = sc;
        ws[OFF_SH + n] = beta[n] - mean * sc;
    }
}

// out = (x1 + relu(tt*sc[n]+sh[n])) * gate + hbias, in place. grid 8192, 8 elems/thread
__global__ void k8_final(float* __restrict__ out, const float* __restrict__ ws) {
    unsigned idx = blockIdx.x * 256u + threadIdx.x;
    unsigned o8 = (idx & 31u) * 8u;
    unsigned n  = (idx >> 5) & (NN - 1u);
    unsigned b  = idx >> 16;
    size_t base = (size_t)((b * NN + n) * DOUT) + o8;
    const unsigned short* ttb = (const unsigned short*)(ws + OFF_TT);
    float4 x0 = ((const float4*)(out + base))[0];
    float4 x1 = ((const float4*)(out + base))[1];
    ushort4 ta = ((const ushort4*)(ttb + base))[0];
    ushort4 tc = ((const ushort4*)(ttb + base))[1];
    float sc = ws[OFF_SC + n], sh = ws[OFF_SH + n];
    const float* gp  = ws + OFF_G  + b * DOUT + o8;
    const float* hbp = ws + OFF_HB + b * DOUT + o8;
    float4 g0 = ((const float4*)gp)[0],  g1 = ((const float4*)gp)[1];
    float4 h0 = ((const float4*)hbp)[0], h1 = ((const float4*)hbp)[1];
    float4 o0, o1;
    o0.x = (x0.x + fmaxf(bf2f(ta.x) * sc + sh, 0.f)) * g0.x + h0.x;
    o0.y = (x0.y + fmaxf(bf2f(ta.y) * sc + sh, 0.f)) * g0.y + h0.y;
    o0.z = (x0.z + fmaxf(bf2f(ta.z) * sc + sh, 0.f)) * g0.z + h0.z;
    o0.w = (x0.w + fmaxf(bf2f(ta.w) * sc + sh, 0.f)) * g0.w + h0.w;
    o1.x = (x1.x + fmaxf(bf2f(tc.x) * sc + sh, 0.f)) * g1.x + h1.x;
    o1.y = (x1.y + fmaxf(bf2f(tc.y) * sc + sh, 0.f)) * g1.y + h1.y;
    o1.z = (x1.z + fmaxf(bf2f(tc.z) * sc + sh, 0.f)) * g1.z + h1.z;
    o1.w = (x1.w + fmaxf(bf2f(tc.w) * sc + sh, 0.f)) * g1.w + h1.w;
    ((float4*)(out + base))[0] = o0;
    ((float4*)(out + base))[1] = o1;
}

extern "C" void kernel_launch(void* const* d_in, const int* in_sizes, int n_in,
                              void* d_out, int out_size, void* d_ws, size_t ws_size,
                              hipStream_t stream) {
    const float* ctx   = (const float*)d_in[0];
    const float* x     = (const float*)d_in[1];
    const float* Wl    = (const float*)d_in[2];
    const float* bl    = (const float*)d_in[3];
    const float* Whb   = (const float*)d_in[4];
    const float* Wg    = (const float*)d_in[5];
    const float* bg    = (const float*)d_in[6];
    const float* Wk    = (const float*)d_in[7];
    const float* Wv    = (const float*)d_in[8];
    const float* Wtc   = (const float*)d_in[9];
    const float* btc   = (const float*)d_in[10];
    const float* gamma = (const float*)d_in[11];
    const float* beta  = (const float*)d_in[12];
    float* out = (float*)d_out;
    float* ws  = (float*)d_ws;

    kXW      <<<8202, 256, 0, stream>>>(x, Wl, Wtc, ws);
    kP       <<<BB, 256, 0, stream>>>(ctx, Wk, Wv, Wg, bg, Whb, ws);
    k4m      <<<dim3(4, BB), 256, 0, stream>>>(ws);
    k5m      <<<dim3(2, BB), 256, 0, stream>>>(bl, btc, ws);
    k6_mfma  <<<dim3(64, BB), 256, 0, stream>>>(bl, out, ws);
    k7_stats <<<NN, 256, 0, stream>>>(gamma, beta, ws);
    k8_final <<<8192, 256, 0, stream>>>(out, ws);
}

// Round 5
// 268.024 us; speedup vs baseline: 1.8132x; 1.1832x over previous
//
#include <hip/hip_runtime.h>
#include <hip/hip_bf16.h>

#define BB   32
#define NN   2048
#define DIN  128
#define DOUT 256
#define DCTX 259

// ---- workspace layout (float-slot offsets) ----
// TT bf16 [B][N][256] = 8388608 slots. A and Mt alias inside TT (dead before k6 writes TT).
#define OFF_TT   0u
#define OFF_AB   0u          // A  bf16 [B][256][256] = 1048576 slots
#define OFF_MTB  1048576u    // Mt bf16 [B][256][256] = 1048576 slots
#define OFF_XB   8388608u    // x bf16 [B][N][128] = 4194304 slots
#define OFF_WMB  12582912u   // WM bf16 [B][256 e][128 i] = 524288 slots
#define OFF_WLB  13107200u   // W_layer bf16 [256 o][128 i] = 16384 slots
#define OFF_WLTB 13123584u   // W_layer^T bf16 [128 i][256 o] = 16384 slots
#define OFF_WTCB 13139968u   // W_tc bf16 [256 e][256 o] = 32768 slots
#define OFF_G    13172736u
#define OFF_HB   13180928u
#define OFF_TB   13189120u
#define OFF_SC   13197312u
#define OFF_SH   13199360u
// transposed fp32 projection weights (coalesced GEMV reads in kP):
#define OFF_WKT  13201408u   // [256 c][256 o]
#define OFF_WVT  13266944u   // [256 c][256 o]
#define OFF_WGT  13332480u   // [259 c][256 o]
#define OFF_WHT  13398784u   // [259 c][256 o]
// total 13465088 slots = 53.9 MB

typedef short bf16x8 __attribute__((ext_vector_type(8)));
typedef float f32x4  __attribute__((ext_vector_type(4)));

static __device__ inline unsigned short f2bf(float f) {
    __hip_bfloat16 h = __float2bfloat16(f);
    return *(unsigned short*)&h;
}
static __device__ inline float bf2f(unsigned short u) {
    unsigned v = ((unsigned)u) << 16;
    float f;
    __builtin_memcpy(&f, &v, 4);
    return f;
}

// x fp32->bf16, pack Wtc/Wl/Wl^T bf16, transpose Wk/Wv/Wg/Whb fp32. grid 8236.
__global__ void kXW(const float* __restrict__ x, const float* __restrict__ Wl,
                    const float* __restrict__ Wtc,
                    const float* __restrict__ Wk, const float* __restrict__ Wv,
                    const float* __restrict__ Wg, const float* __restrict__ Whb,
                    float* __restrict__ ws) {
    unsigned bb = blockIdx.x, t = threadIdx.x;
    if (bb < 8192u) {
        unsigned i = bb * 256u + t;
        float4 v = ((const float4*)x)[i];
        ushort4 o;
        o.x = f2bf(v.x); o.y = f2bf(v.y); o.z = f2bf(v.z); o.w = f2bf(v.w);
        ((ushort4*)(ws + OFF_XB))[i] = o;
    } else if (bb < 8200u) {
        unsigned base = (bb - 8192u) * 8192u;
        unsigned short* dst = (unsigned short*)(ws + OFF_WTCB);
#pragma unroll
        for (int j = 0; j < 32; j++) {
            unsigned i = base + (unsigned)j * 256u + t;
            dst[i] = f2bf(Wtc[i]);
        }
    } else if (bb == 8200u) {
        unsigned short* dst = (unsigned short*)(ws + OFF_WLTB);   // [i][o]
        for (unsigned idx = t; idx < 32768u; idx += 256u) {
            unsigned i = idx >> 8, o = idx & 255u;
            dst[idx] = f2bf(Wl[o * 128u + i]);
        }
    } else if (bb == 8201u) {
        unsigned short* dst = (unsigned short*)(ws + OFF_WLB);    // [o][i]
        for (unsigned idx = t; idx < 32768u; idx += 256u) dst[idx] = f2bf(Wl[idx]);
    } else {
        // fp32 transposes: dst[c][o] = src[o][c]; writes coalesced (lane = o).
        unsigned j = bb - 8202u;
        const float* src; float* dst; unsigned C, c0;
        if (j < 8u)       { src = Wk;  dst = ws + OFF_WKT; C = 256; c0 = j * 32u; }
        else if (j < 16u) { src = Wv;  dst = ws + OFF_WVT; C = 256; c0 = (j - 8u) * 32u; }
        else if (j < 25u) { src = Wg;  dst = ws + OFF_WGT; C = 259; c0 = (j - 16u) * 32u; }
        else              { src = Whb; dst = ws + OFF_WHT; C = 259; c0 = (j - 25u) * 32u; }
        for (unsigned cc = c0; cc < c0 + 32u && cc < C; cc++)
            dst[cc * 256u + t] = src[t * C + cc];
    }
}

// Fused prep, 1024 threads: coalesced GEMVs (q = matrix, o = output), 4-way-split
// softmax stats + A bf16 materialization. grid B.
__global__ __launch_bounds__(1024) void kP(const float* __restrict__ ctx,
                                           const float* __restrict__ bg,
                                           float* __restrict__ ws) {
    const int b = blockIdx.x, t = threadIdx.x;
    const int o = t & 255, q = t >> 8;
    __shared__ __align__(16) float cs[260];
    __shared__ __align__(16) float ks[256], vs[256], rms[256], ris[256];
    __shared__ float pm[1024], ps[1024];
    for (int i = t; i < DCTX; i += 1024) cs[i] = ctx[b * DCTX + i];
    __syncthreads();

    {   // coalesced GEMV: lane o consecutive -> consecutive addresses
        const float* WT; int C;
        if (q == 0)      { WT = ws + OFF_WKT; C = 256; }
        else if (q == 1) { WT = ws + OFF_WVT; C = 256; }
        else if (q == 2) { WT = ws + OFF_WGT; C = DCTX; }
        else             { WT = ws + OFF_WHT; C = DCTX; }
        float s = 0.f;
#pragma unroll 8
        for (int c = 0; c < C; c++) s += WT[c * 256 + o] * cs[c];
        if (q == 0)      ks[o] = s;
        else if (q == 1) vs[o] = s;
        else if (q == 2) ws[OFF_G + b * DOUT + o] = 1.f / (1.f + __expf(-(s + bg[o])));
        else             ws[OFF_HB + b * DOUT + o] = s;
    }
    __syncthreads();

    const float ko = ks[o];
    const float4* vs4 = (const float4*)vs;
    // stage 1: partial row max over e in [q*64, q*64+64)
    float pmax = -1e30f;
#pragma unroll 4
    for (int j = q * 16; j < q * 16 + 16; j++) {
        float4 v = vs4[j];
        pmax = fmaxf(pmax, fmaxf(fmaxf(ko * v.x, ko * v.y), fmaxf(ko * v.z, ko * v.w)));
    }
    pm[q * 256 + o] = pmax;
    __syncthreads();
    float m = fmaxf(fmaxf(pm[o], pm[256 + o]), fmaxf(pm[512 + o], pm[768 + o]));
    // stage 2: partial row sum
    float psum = 0.f;
#pragma unroll 4
    for (int j = q * 16; j < q * 16 + 16; j++) {
        float4 v = vs4[j];
        psum += __expf(ko * v.x - m) + __expf(ko * v.y - m)
              + __expf(ko * v.z - m) + __expf(ko * v.w - m);
    }
    ps[q * 256 + o] = psum;
    __syncthreads();
    float ri = 1.f / (ps[o] + ps[256 + o] + ps[512 + o] + ps[768 + o]);
    if (q == 0) { rms[o] = m; ris[o] = ri; }
    __syncthreads();

    // col partials: this thread owns col e=o, rows o2 in [q*64, q*64+64)
    const float ve = vs[o];
    float cp = 0.f;
#pragma unroll 4
    for (int o2 = q * 64; o2 < q * 64 + 64; o2++)
        cp += __expf(ks[o2] * ve - rms[o2]) * ris[o2];
    pm[q * 256 + o] = cp;   // safe reuse: last pm read was 2 syncs ago
    __syncthreads();
    float ci = 1.f / (1e-9f + pm[o] + pm[256 + o] + pm[512 + o] + pm[768 + o]);
    unsigned short* Ab = (unsigned short*)(ws + OFF_AB) + (size_t)b * 65536u;
#pragma unroll 4
    for (int o2 = q * 64; o2 < q * 64 + 64; o2++) {
        float a = __expf(ks[o2] * ve - rms[o2]) * ris[o2] * ci;
        Ab[o2 * 256 + o] = f2bf(a);   // lanes consecutive o -> coalesced
    }
}

// Mt[e][o] = Wtc[e][o] - sum_o' Wtc[e][o'] * A[o][o']  (MFMA). grid (4 e-tiles, B).
__global__ __launch_bounds__(256) void k4m(float* __restrict__ ws) {
    const int t = threadIdx.x, wid = t >> 6, l = t & 63;
    const int b = blockIdx.y, et = blockIdx.x;
    const int lrow = l & 15, lk = l >> 4;
    const int rbase = et * 64 + (wid & 1) * 32;
    const int colbase = (wid >> 1) * 128;
    const unsigned short* Wtcb = (const unsigned short*)(ws + OFF_WTCB);
    const unsigned short* Ab = (const unsigned short*)(ws + OFF_AB) + (size_t)b * 65536u;

    f32x4 acc[2][8];
#pragma unroll
    for (int i = 0; i < 2; i++)
#pragma unroll
        for (int c = 0; c < 8; c++) acc[i][c] = (f32x4){0.f, 0.f, 0.f, 0.f};

    const unsigned short* ar0 = Wtcb + (rbase + lrow) * 256;
#pragma unroll
    for (int kk = 0; kk < 8; kk++) {
        int ko = kk * 32 + lk * 8;
        bf16x8 a0 = *(const bf16x8*)(ar0 + ko);
        bf16x8 a1 = *(const bf16x8*)(ar0 + 16 * 256 + ko);
        bf16x8 bfr[8];
#pragma unroll
        for (int c = 0; c < 8; c++)
            bfr[c] = *(const bf16x8*)(Ab + (colbase + c * 16 + lrow) * 256 + ko);
#pragma unroll
        for (int c = 0; c < 8; c++) {
            acc[0][c] = __builtin_amdgcn_mfma_f32_16x16x32_bf16(a0, bfr[c], acc[0][c], 0, 0, 0);
            acc[1][c] = __builtin_amdgcn_mfma_f32_16x16x32_bf16(a1, bfr[c], acc[1][c], 0, 0, 0);
        }
    }
    unsigned short* Mtb = (unsigned short*)(ws + OFF_MTB) + (size_t)b * 65536u;
#pragma unroll
    for (int t2 = 0; t2 < 2; t2++)
#pragma unroll
        for (int c = 0; c < 8; c++)
#pragma unroll
            for (int r = 0; r < 4; r++) {
                int row = rbase + t2 * 16 + lk * 4 + r;
                int col = colbase + c * 16 + lrow;
                float idv = bf2f(Wtcb[row * 256 + col]);
                Mtb[row * 256 + col] = f2bf(idv - acc[t2][c][r]);
            }
}

// WM[e][i] = sum_o Mt[e][o] * Wl^T[i][o]  (MFMA) + tbias. grid (2 e-tiles, B).
__global__ __launch_bounds__(256) void k5m(const float* __restrict__ bl,
                                           const float* __restrict__ btc,
                                           float* __restrict__ ws) {
    const int t = threadIdx.x, wid = t >> 6, l = t & 63;
    const int b = blockIdx.y, et = blockIdx.x;
    const int lrow = l & 15, lk = l >> 4;
    const int rbase = et * 128 + wid * 32;
    const unsigned short* Mtb = (const unsigned short*)(ws + OFF_MTB) + (size_t)b * 65536u;
    const unsigned short* Wltb = (const unsigned short*)(ws + OFF_WLTB);

    f32x4 acc[2][8];
#pragma unroll
    for (int i = 0; i < 2; i++)
#pragma unroll
        for (int c = 0; c < 8; c++) acc[i][c] = (f32x4){0.f, 0.f, 0.f, 0.f};

    const unsigned short* ar0 = Mtb + (rbase + lrow) * 256;
#pragma unroll
    for (int kk = 0; kk < 8; kk++) {
        int ko = kk * 32 + lk * 8;
        bf16x8 a0 = *(const bf16x8*)(ar0 + ko);
        bf16x8 a1 = *(const bf16x8*)(ar0 + 16 * 256 + ko);
        bf16x8 bfr[8];
#pragma unroll
        for (int c = 0; c < 8; c++)
            bfr[c] = *(const bf16x8*)(Wltb + (c * 16 + lrow) * 256 + ko);
#pragma unroll
        for (int c = 0; c < 8; c++) {
            acc[0][c] = __builtin_amdgcn_mfma_f32_16x16x32_bf16(a0, bfr[c], acc[0][c], 0, 0, 0);
            acc[1][c] = __builtin_amdgcn_mfma_f32_16x16x32_bf16(a1, bfr[c], acc[1][c], 0, 0, 0);
        }
    }
    unsigned short* WMBp = (unsigned short*)(ws + OFF_WMB) + (size_t)b * 32768u;
#pragma unroll
    for (int t2 = 0; t2 < 2; t2++)
#pragma unroll
        for (int c = 0; c < 8; c++)
#pragma unroll
            for (int r = 0; r < 4; r++) {
                int row = rbase + t2 * 16 + lk * 4 + r;   // e
                int col = c * 16 + lrow;                  // i
                WMBp[row * 128 + col] = f2bf(acc[t2][c][r]);
            }
    if (t < 128) {
        int e = et * 128 + t;
        const unsigned short* mrow = Mtb + e * 256;
        float s = 0.f;
#pragma unroll 8
        for (int o = 0; o < 256; o++) s += bl[o] * bf2f(mrow[o]);
        ws[OFF_TB + b * DOUT + e] = s + btc[e];
    }
}

// dual GEMM via MFMA bf16: waves 0,1: x1 -> d_out (fp32); waves 2,3: tt -> ws TT (bf16)
__global__ __launch_bounds__(256) void k6_mfma(const float* __restrict__ bl,
                                               float* __restrict__ out,
                                               float* __restrict__ ws) {
    const int t = threadIdx.x;
    const int wid = t >> 6, l = t & 63;
    const int b = blockIdx.y;
    const int n0 = blockIdx.x * 32;
    const int lrow = l & 15, lk = l >> 4;

    const unsigned short* xb = (const unsigned short*)(ws + OFF_XB);
    const unsigned short* wb;
    int colbase;
    if (wid < 2) { wb = (const unsigned short*)(ws + OFF_WLB); colbase = wid * 128; }
    else         { wb = (const unsigned short*)(ws + OFF_WMB) + (size_t)b * DOUT * DIN; colbase = (wid - 2) * 128; }

    float bias[8];
#pragma unroll
    for (int c = 0; c < 8; c++) {
        int col = colbase + c * 16 + lrow;
        bias[c] = (wid < 2) ? bl[col] : ws[OFF_TB + b * DOUT + col];
    }

    f32x4 acc[2][8];
#pragma unroll
    for (int i = 0; i < 2; i++)
#pragma unroll
        for (int c = 0; c < 8; c++) acc[i][c] = (f32x4){0.f, 0.f, 0.f, 0.f};

    const unsigned short* xr0 = xb + (size_t)((b * NN + n0 + lrow) * DIN);
#pragma unroll
    for (int kk = 0; kk < 4; kk++) {
        int ko = kk * 32 + lk * 8;
        bf16x8 a0 = *(const bf16x8*)(xr0 + ko);
        bf16x8 a1 = *(const bf16x8*)(xr0 + 16 * DIN + ko);
        bf16x8 bfr[8];
#pragma unroll
        for (int c = 0; c < 8; c++)
            bfr[c] = *(const bf16x8*)(wb + (size_t)((colbase + c * 16 + lrow) * DIN) + ko);
#pragma unroll
        for (int c = 0; c < 8; c++) {
            acc[0][c] = __builtin_amdgcn_mfma_f32_16x16x32_bf16(a0, bfr[c], acc[0][c], 0, 0, 0);
            acc[1][c] = __builtin_amdgcn_mfma_f32_16x16x32_bf16(a1, bfr[c], acc[1][c], 0, 0, 0);
        }
    }

    if (wid < 2) {
#pragma unroll
        for (int t2 = 0; t2 < 2; t2++)
#pragma unroll
            for (int c = 0; c < 8; c++)
#pragma unroll
                for (int r = 0; r < 4; r++) {
                    int row = n0 + t2 * 16 + lk * 4 + r;
                    int col = colbase + c * 16 + lrow;
                    out[(size_t)((b * NN + row) * DOUT) + col] = acc[t2][c][r] + bias[c];
                }
    } else {
        unsigned short* ttp = (unsigned short*)(ws + OFF_TT);
#pragma unroll
        for (int t2 = 0; t2 < 2; t2++)
#pragma unroll
            for (int c = 0; c < 8; c++)
#pragma unroll
                for (int r = 0; r < 4; r++) {
                    int row = n0 + t2 * 16 + lk * 4 + r;
                    int col = colbase + c * 16 + lrow;
                    ttp[(size_t)((b * NN + row) * DOUT) + col] = f2bf(acc[t2][c][r] + bias[c]);
                }
    }
}

// BN stats per n over (b,e) from bf16 tt. grid N
__global__ void k7_stats(const float* __restrict__ gamma, const float* __restrict__ beta,
                         float* __restrict__ ws) {
    int n = blockIdx.x, t = threadIdx.x;
    const unsigned short* ttb = (const unsigned short*)(ws + OFF_TT);
    float s1 = 0.f, s2 = 0.f;
    for (int b = 0; b < BB; b++) {
        float v = bf2f(ttb[(size_t)((b * NN + n) * DOUT) + t]);
        s1 += v; s2 += v * v;
    }
    for (int off = 32; off > 0; off >>= 1) {
        s1 += __shfl_down(s1, off, 64);
        s2 += __shfl_down(s2, off, 64);
    }
    __shared__ float p1[4], p2[4];
    if ((t & 63) == 0) { p1[t >> 6] = s1; p2[t >> 6] = s2; }
    __syncthreads();
    if (t == 0) {
        float S1 = p1[0] + p1[1] + p1[2] + p1[3];
        float S2 = p2[0] + p2[1] + p2[2] + p2[3];
        float mean = S1 * (1.f / 8192.f);
        float var  = S2 * (1.f / 8192.f) - mean * mean;
        float sc = gamma[n] * rsqrtf(fmaxf(var, 0.f) + 1e-5f);
        ws[OFF_SC + n] = sc;
        ws[OFF_SH + n] = beta[n] - mean * sc;
    }
}

// out = (x1 + relu(tt*sc[n]+sh[n])) * gate + hbias, in place. grid 8192, 8 elems/thread
__global__ void k8_final(float* __restrict__ out, const float* __restrict__ ws) {
    unsigned idx = blockIdx.x * 256u + threadIdx.x;
    unsigned o8 = (idx & 31u) * 8u;
    unsigned n  = (idx >> 5) & (NN - 1u);
    unsigned b  = idx >> 16;
    size_t base = (size_t)((b * NN + n) * DOUT) + o8;
    const unsigned short* ttb = (const unsigned short*)(ws + OFF_TT);
    float4 x0 = ((const float4*)(out + base))[0];
    float4 x1 = ((const float4*)(out + base))[1];
    ushort4 ta = ((const ushort4*)(ttb + base))[0];
    ushort4 tc = ((const ushort4*)(ttb + base))[1];
    float sc = ws[OFF_SC + n], sh = ws[OFF_SH + n];
    const float* gp  = ws + OFF_G  + b * DOUT + o8;
    const float* hbp = ws + OFF_HB + b * DOUT + o8;
    float4 g0 = ((const float4*)gp)[0],  g1 = ((const float4*)gp)[1];
    float4 h0 = ((const float4*)hbp)[0], h1 = ((const float4*)hbp)[1];
    float4 o0, o1;
    o0.x = (x0.x + fmaxf(bf2f(ta.x) * sc + sh, 0.f)) * g0.x + h0.x;
    o0.y = (x0.y + fmaxf(bf2f(ta.y) * sc + sh, 0.f)) * g0.y + h0.y;
    o0.z = (x0.z + fmaxf(bf2f(ta.z) * sc + sh, 0.f)) * g0.z + h0.z;
    o0.w = (x0.w + fmaxf(bf2f(ta.w) * sc + sh, 0.f)) * g0.w + h0.w;
    o1.x = (x1.x + fmaxf(bf2f(tc.x) * sc + sh, 0.f)) * g1.x + h1.x;
    o1.y = (x1.y + fmaxf(bf2f(tc.y) * sc + sh, 0.f)) * g1.y + h1.y;
    o1.z = (x1.z + fmaxf(bf2f(tc.z) * sc + sh, 0.f)) * g1.z + h1.z;
    o1.w = (x1.w + fmaxf(bf2f(tc.w) * sc + sh, 0.f)) * g1.w + h1.w;
    ((float4*)(out + base))[0] = o0;
    ((float4*)(out + base))[1] = o1;
}

extern "C" void kernel_launch(void* const* d_in, const int* in_sizes, int n_in,
                              void* d_out, int out_size, void* d_ws, size_t ws_size,
                              hipStream_t stream) {
    const float* ctx   = (const float*)d_in[0];
    const float* x     = (const float*)d_in[1];
    const float* Wl    = (const float*)d_in[2];
    const float* bl    = (const float*)d_in[3];
    const float* Whb   = (const float*)d_in[4];
    const float* Wg    = (const float*)d_in[5];
    const float* bg    = (const float*)d_in[6];
    const float* Wk    = (const float*)d_in[7];
    const float* Wv    = (const float*)d_in[8];
    const float* Wtc   = (const float*)d_in[9];
    const float* btc   = (const float*)d_in[10];
    const float* gamma = (const float*)d_in[11];
    const float* beta  = (const float*)d_in[12];
    float* out = (float*)d_out;
    float* ws  = (float*)d_ws;

    kXW      <<<8236, 256, 0, stream>>>(x, Wl, Wtc, Wk, Wv, Wg, Whb, ws);
    kP       <<<BB, 1024, 0, stream>>>(ctx, bg, ws);
    k4m      <<<dim3(4, BB), 256, 0, stream>>>(ws);
    k5m      <<<dim3(2, BB), 256, 0, stream>>>(bl, btc, ws);
    k6_mfma  <<<dim3(64, BB), 256, 0, stream>>>(bl, out, ws);
    k7_stats <<<NN, 256, 0, stream>>>(gamma, beta, ws);
    k8_final <<<8192, 256, 0, stream>>>(out, ws);
}

// Round 6
// 259.210 us; speedup vs baseline: 1.8749x; 1.0340x over previous
//
#include <hip/hip_runtime.h>
#include <hip/hip_bf16.h>

#define BB   32
#define NN   2048
#define DIN  128
#define DOUT 256
#define DCTX 259

// ---- workspace layout (float-slot offsets) ----
#define OFF_TT   0u          // tt  bf16 [B][N][256] = 8388608 slots
#define OFF_AB   0u          // A  bf16 [B][256][256] (alias TT; dead before k6)
#define OFF_MTB  1048576u    // Mt bf16 [B][256][256] (alias TT; dead before k6)
#define OFF_X1B  8388608u    // x1 bf16 [B][N][256] = 8388608 slots
#define OFF_WMB  16777216u   // WM bf16 [B][256 e][128 i] = 524288
#define OFF_WLB  17301504u   // W_layer bf16 [256 o][128 i] = 16384
#define OFF_WLTB 17317888u   // W_layer^T bf16 [128 i][256 o] = 16384
#define OFF_WTCB 17334272u   // W_tc bf16 [256 e][256 o] = 32768
#define OFF_G    17367040u
#define OFF_HB   17375232u
#define OFF_TB   17383424u
#define OFF_WKT  17391616u   // [256 c][256 o] fp32
#define OFF_WVT  17457152u
#define OFF_WGT  17522688u   // [259 c][256 o]
#define OFF_WHT  17588992u
// end 17655296 slots = 70.6 MB

typedef short bf16x8 __attribute__((ext_vector_type(8)));
typedef float f32x4  __attribute__((ext_vector_type(4)));

static __device__ inline unsigned short f2bf(float f) {
    __hip_bfloat16 h = __float2bfloat16(f);
    return *(unsigned short*)&h;
}
static __device__ inline float bf2f(unsigned short u) {
    unsigned v = ((unsigned)u) << 16;
    float f;
    __builtin_memcpy(&f, &v, 4);
    return f;
}

// weight packing only: Wtc bf16, Wl/Wl^T bf16, Wk/Wv/Wg/Whb fp32 transposes. grid 44.
__global__ void kXW(const float* __restrict__ Wl, const float* __restrict__ Wtc,
                    const float* __restrict__ Wk, const float* __restrict__ Wv,
                    const float* __restrict__ Wg, const float* __restrict__ Whb,
                    float* __restrict__ ws) {
    unsigned bb = blockIdx.x, t = threadIdx.x;
    if (bb < 8u) {
        unsigned base = bb * 8192u;
        unsigned short* dst = (unsigned short*)(ws + OFF_WTCB);
#pragma unroll
        for (int j = 0; j < 32; j++) {
            unsigned i = base + (unsigned)j * 256u + t;
            dst[i] = f2bf(Wtc[i]);
        }
    } else if (bb == 8u) {
        unsigned short* dst = (unsigned short*)(ws + OFF_WLTB);   // [i][o]
        for (unsigned idx = t; idx < 32768u; idx += 256u) {
            unsigned i = idx >> 8, o = idx & 255u;
            dst[idx] = f2bf(Wl[o * 128u + i]);
        }
    } else if (bb == 9u) {
        unsigned short* dst = (unsigned short*)(ws + OFF_WLB);    // [o][i]
        for (unsigned idx = t; idx < 32768u; idx += 256u) dst[idx] = f2bf(Wl[idx]);
    } else {
        unsigned j = bb - 10u;
        const float* src; float* dst; unsigned C, c0;
        if (j < 8u)       { src = Wk;  dst = ws + OFF_WKT; C = 256; c0 = j * 32u; }
        else if (j < 16u) { src = Wv;  dst = ws + OFF_WVT; C = 256; c0 = (j - 8u) * 32u; }
        else if (j < 25u) { src = Wg;  dst = ws + OFF_WGT; C = 259; c0 = (j - 16u) * 32u; }
        else              { src = Whb; dst = ws + OFF_WHT; C = 259; c0 = (j - 25u) * 32u; }
        for (unsigned cc = c0; cc < c0 + 32u && cc < C; cc++)
            dst[cc * 256u + t] = src[t * C + cc];
    }
}

// Fused prep, 1024 threads: coalesced GEMVs + split softmax stats + A bf16. grid B.
__global__ __launch_bounds__(1024) void kP(const float* __restrict__ ctx,
                                           const float* __restrict__ bg,
                                           float* __restrict__ ws) {
    const int b = blockIdx.x, t = threadIdx.x;
    const int o = t & 255, q = t >> 8;
    __shared__ __align__(16) float cs[260];
    __shared__ __align__(16) float ks[256], vs[256], rms[256], ris[256];
    __shared__ float pm[1024], ps[1024];
    for (int i = t; i < DCTX; i += 1024) cs[i] = ctx[b * DCTX + i];
    __syncthreads();

    {
        const float* WT; int C;
        if (q == 0)      { WT = ws + OFF_WKT; C = 256; }
        else if (q == 1) { WT = ws + OFF_WVT; C = 256; }
        else if (q == 2) { WT = ws + OFF_WGT; C = DCTX; }
        else             { WT = ws + OFF_WHT; C = DCTX; }
        float s = 0.f;
#pragma unroll 8
        for (int c = 0; c < C; c++) s += WT[c * 256 + o] * cs[c];
        if (q == 0)      ks[o] = s;
        else if (q == 1) vs[o] = s;
        else if (q == 2) ws[OFF_G + b * DOUT + o] = 1.f / (1.f + __expf(-(s + bg[o])));
        else             ws[OFF_HB + b * DOUT + o] = s;
    }
    __syncthreads();

    const float ko = ks[o];
    const float4* vs4 = (const float4*)vs;
    float pmax = -1e30f;
#pragma unroll 4
    for (int j = q * 16; j < q * 16 + 16; j++) {
        float4 v = vs4[j];
        pmax = fmaxf(pmax, fmaxf(fmaxf(ko * v.x, ko * v.y), fmaxf(ko * v.z, ko * v.w)));
    }
    pm[q * 256 + o] = pmax;
    __syncthreads();
    float m = fmaxf(fmaxf(pm[o], pm[256 + o]), fmaxf(pm[512 + o], pm[768 + o]));
    float psum = 0.f;
#pragma unroll 4
    for (int j = q * 16; j < q * 16 + 16; j++) {
        float4 v = vs4[j];
        psum += __expf(ko * v.x - m) + __expf(ko * v.y - m)
              + __expf(ko * v.z - m) + __expf(ko * v.w - m);
    }
    ps[q * 256 + o] = psum;
    __syncthreads();
    float ri = 1.f / (ps[o] + ps[256 + o] + ps[512 + o] + ps[768 + o]);
    if (q == 0) { rms[o] = m; ris[o] = ri; }
    __syncthreads();

    const float ve = vs[o];
    float cp = 0.f;
#pragma unroll 4
    for (int o2 = q * 64; o2 < q * 64 + 64; o2++)
        cp += __expf(ks[o2] * ve - rms[o2]) * ris[o2];
    pm[q * 256 + o] = cp;
    __syncthreads();
    float ci = 1.f / (1e-9f + pm[o] + pm[256 + o] + pm[512 + o] + pm[768 + o]);
    unsigned short* Ab = (unsigned short*)(ws + OFF_AB) + (size_t)b * 65536u;
#pragma unroll 4
    for (int o2 = q * 64; o2 < q * 64 + 64; o2++) {
        float a = __expf(ks[o2] * ve - rms[o2]) * ris[o2] * ci;
        Ab[o2 * 256 + o] = f2bf(a);
    }
}

// Mt[e][o] = Wtc[e][o] - sum_o' Wtc[e][o'] * A[o][o']  (MFMA). grid (4 e-tiles, B).
__global__ __launch_bounds__(256) void k4m(float* __restrict__ ws) {
    const int t = threadIdx.x, wid = t >> 6, l = t & 63;
    const int b = blockIdx.y, et = blockIdx.x;
    const int lrow = l & 15, lk = l >> 4;
    const int rbase = et * 64 + (wid & 1) * 32;
    const int colbase = (wid >> 1) * 128;
    const unsigned short* Wtcb = (const unsigned short*)(ws + OFF_WTCB);
    const unsigned short* Ab = (const unsigned short*)(ws + OFF_AB) + (size_t)b * 65536u;

    f32x4 acc[2][8];
#pragma unroll
    for (int i = 0; i < 2; i++)
#pragma unroll
        for (int c = 0; c < 8; c++) acc[i][c] = (f32x4){0.f, 0.f, 0.f, 0.f};

    const unsigned short* ar0 = Wtcb + (rbase + lrow) * 256;
#pragma unroll
    for (int kk = 0; kk < 8; kk++) {
        int ko = kk * 32 + lk * 8;
        bf16x8 a0 = *(const bf16x8*)(ar0 + ko);
        bf16x8 a1 = *(const bf16x8*)(ar0 + 16 * 256 + ko);
        bf16x8 bfr[8];
#pragma unroll
        for (int c = 0; c < 8; c++)
            bfr[c] = *(const bf16x8*)(Ab + (colbase + c * 16 + lrow) * 256 + ko);
#pragma unroll
        for (int c = 0; c < 8; c++) {
            acc[0][c] = __builtin_amdgcn_mfma_f32_16x16x32_bf16(a0, bfr[c], acc[0][c], 0, 0, 0);
            acc[1][c] = __builtin_amdgcn_mfma_f32_16x16x32_bf16(a1, bfr[c], acc[1][c], 0, 0, 0);
        }
    }
    unsigned short* Mtb = (unsigned short*)(ws + OFF_MTB) + (size_t)b * 65536u;
#pragma unroll
    for (int t2 = 0; t2 < 2; t2++)
#pragma unroll
        for (int c = 0; c < 8; c++)
#pragma unroll
            for (int r = 0; r < 4; r++) {
                int row = rbase + t2 * 16 + lk * 4 + r;
                int col = colbase + c * 16 + lrow;
                float idv = bf2f(Wtcb[row * 256 + col]);
                Mtb[row * 256 + col] = f2bf(idv - acc[t2][c][r]);
            }
}

// WM[e][i] = sum_o Mt[e][o] * Wl^T[i][o]  (MFMA) + tbias. grid (2 e-tiles, B).
__global__ __launch_bounds__(256) void k5m(const float* __restrict__ bl,
                                           const float* __restrict__ btc,
                                           float* __restrict__ ws) {
    const int t = threadIdx.x, wid = t >> 6, l = t & 63;
    const int b = blockIdx.y, et = blockIdx.x;
    const int lrow = l & 15, lk = l >> 4;
    const int rbase = et * 128 + wid * 32;
    const unsigned short* Mtb = (const unsigned short*)(ws + OFF_MTB) + (size_t)b * 65536u;
    const unsigned short* Wltb = (const unsigned short*)(ws + OFF_WLTB);

    f32x4 acc[2][8];
#pragma unroll
    for (int i = 0; i < 2; i++)
#pragma unroll
        for (int c = 0; c < 8; c++) acc[i][c] = (f32x4){0.f, 0.f, 0.f, 0.f};

    const unsigned short* ar0 = Mtb + (rbase + lrow) * 256;
#pragma unroll
    for (int kk = 0; kk < 8; kk++) {
        int ko = kk * 32 + lk * 8;
        bf16x8 a0 = *(const bf16x8*)(ar0 + ko);
        bf16x8 a1 = *(const bf16x8*)(ar0 + 16 * 256 + ko);
        bf16x8 bfr[8];
#pragma unroll
        for (int c = 0; c < 8; c++)
            bfr[c] = *(const bf16x8*)(Wltb + (c * 16 + lrow) * 256 + ko);
#pragma unroll
        for (int c = 0; c < 8; c++) {
            acc[0][c] = __builtin_amdgcn_mfma_f32_16x16x32_bf16(a0, bfr[c], acc[0][c], 0, 0, 0);
            acc[1][c] = __builtin_amdgcn_mfma_f32_16x16x32_bf16(a1, bfr[c], acc[1][c], 0, 0, 0);
        }
    }
    unsigned short* WMBp = (unsigned short*)(ws + OFF_WMB) + (size_t)b * 32768u;
#pragma unroll
    for (int t2 = 0; t2 < 2; t2++)
#pragma unroll
        for (int c = 0; c < 8; c++)
#pragma unroll
            for (int r = 0; r < 4; r++) {
                int row = rbase + t2 * 16 + lk * 4 + r;
                int col = c * 16 + lrow;
                WMBp[row * 128 + col] = f2bf(acc[t2][c][r]);
            }
    if (t < 128) {
        int e = et * 128 + t;
        const unsigned short* mrow = Mtb + e * 256;
        float s = 0.f;
#pragma unroll 8
        for (int o = 0; o < 256; o++) s += bl[o] * bf2f(mrow[o]);
        ws[OFF_TB + b * DOUT + e] = s + btc[e];
    }
}

// dual GEMM: x fp32 read + in-reg bf16 cvt; MFMA; LDS-repacked coalesced bf16 stores.
// waves 0,1: x1 -> ws X1B; waves 2,3: tt -> ws TT. grid (64, B).
#define LROW 264   // LDS row stride in shorts (528 B: 16B-aligned, <=4-way write conflict)
__global__ __launch_bounds__(256) void k6_mfma(const float* __restrict__ x,
                                               const float* __restrict__ bl,
                                               float* __restrict__ ws) {
    const int t = threadIdx.x;
    const int wid = t >> 6, l = t & 63;
    const int b = blockIdx.y;
    const int n0 = blockIdx.x * 32;
    const int lrow = l & 15, lk = l >> 4;
    __shared__ unsigned short lds[2 * 32 * LROW];

    const unsigned short* wb;
    int colbase, tensor;
    if (wid < 2) { wb = (const unsigned short*)(ws + OFF_WLB); colbase = wid * 128; tensor = 0; }
    else         { wb = (const unsigned short*)(ws + OFF_WMB) + (size_t)b * DOUT * DIN; colbase = (wid - 2) * 128; tensor = 1; }

    float bias[8];
#pragma unroll
    for (int c = 0; c < 8; c++) {
        int col = colbase + c * 16 + lrow;
        bias[c] = (tensor == 0) ? bl[col] : ws[OFF_TB + b * DOUT + col];
    }

    f32x4 acc[2][8];
#pragma unroll
    for (int i = 0; i < 2; i++)
#pragma unroll
        for (int c = 0; c < 8; c++) acc[i][c] = (f32x4){0.f, 0.f, 0.f, 0.f};

    const float* xr0 = x + (size_t)((b * NN + n0 + lrow) * DIN);
    const float* xr1 = xr0 + 16 * DIN;
#pragma unroll
    for (int kk = 0; kk < 4; kk++) {
        int ko = kk * 32 + lk * 8;
        float4 xa = ((const float4*)(xr0 + ko))[0];
        float4 xc = ((const float4*)(xr0 + ko))[1];
        float4 ya = ((const float4*)(xr1 + ko))[0];
        float4 yc = ((const float4*)(xr1 + ko))[1];
        bf16x8 a0, a1;
        a0[0] = (short)f2bf(xa.x); a0[1] = (short)f2bf(xa.y); a0[2] = (short)f2bf(xa.z); a0[3] = (short)f2bf(xa.w);
        a0[4] = (short)f2bf(xc.x); a0[5] = (short)f2bf(xc.y); a0[6] = (short)f2bf(xc.z); a0[7] = (short)f2bf(xc.w);
        a1[0] = (short)f2bf(ya.x); a1[1] = (short)f2bf(ya.y); a1[2] = (short)f2bf(ya.z); a1[3] = (short)f2bf(ya.w);
        a1[4] = (short)f2bf(yc.x); a1[5] = (short)f2bf(yc.y); a1[6] = (short)f2bf(yc.z); a1[7] = (short)f2bf(yc.w);
        bf16x8 bfr[8];
#pragma unroll
        for (int c = 0; c < 8; c++)
            bfr[c] = *(const bf16x8*)(wb + (size_t)((colbase + c * 16 + lrow) * DIN) + ko);
#pragma unroll
        for (int c = 0; c < 8; c++) {
            acc[0][c] = __builtin_amdgcn_mfma_f32_16x16x32_bf16(a0, bfr[c], acc[0][c], 0, 0, 0);
            acc[1][c] = __builtin_amdgcn_mfma_f32_16x16x32_bf16(a1, bfr[c], acc[1][c], 0, 0, 0);
        }
    }

    // stage to LDS in row-major bf16
    unsigned short* lbase = lds + tensor * 32 * LROW;
#pragma unroll
    for (int t2 = 0; t2 < 2; t2++)
#pragma unroll
        for (int c = 0; c < 8; c++)
#pragma unroll
            for (int r = 0; r < 4; r++) {
                int row = t2 * 16 + lk * 4 + r;
                int col = colbase + c * 16 + lrow;
                lbase[row * LROW + col] = f2bf(acc[t2][c][r] + bias[c]);
            }
    __syncthreads();

    // read back + fully-coalesced 16B stores
    unsigned short* x1p = (unsigned short*)(ws + OFF_X1B);
    unsigned short* ttp = (unsigned short*)(ws + OFF_TT);
#pragma unroll
    for (int it = 0; it < 8; it++) {
        int gid = it * 256 + t;
        int tn = gid >> 10, row = (gid >> 5) & 31, cg = gid & 31;
        bf16x8 vv = *(const bf16x8*)(lds + tn * 32 * LROW + row * LROW + cg * 8);
        unsigned short* dst = (tn == 0) ? x1p : ttp;
        *(bf16x8*)(dst + (size_t)((b * NN + n0 + row) * DOUT) + cg * 8) = vv;
    }
}

// fused BN stats + final epilogue. grid N, thread = e, tt row cached in 32 VGPRs.
__global__ __launch_bounds__(256) void k78(const float* __restrict__ gamma,
                                           const float* __restrict__ beta,
                                           float* __restrict__ out,
                                           float* __restrict__ ws) {
    const int n = blockIdx.x, t = threadIdx.x, wid = t >> 6, l = t & 63;
    const unsigned short* ttb = (const unsigned short*)(ws + OFF_TT);
    const unsigned short* x1b = (const unsigned short*)(ws + OFF_X1B);
    float v[32];
    float s1 = 0.f, s2 = 0.f;
#pragma unroll
    for (int b = 0; b < BB; b++) {
        float vv = bf2f(ttb[((size_t)b * NN + n) * DOUT + t]);
        v[b] = vv; s1 += vv; s2 += vv * vv;
    }
#pragma unroll
    for (int off = 32; off > 0; off >>= 1) {
        s1 += __shfl_xor(s1, off, 64);
        s2 += __shfl_xor(s2, off, 64);
    }
    __shared__ float p1[4], p2[4];
    if (l == 0) { p1[wid] = s1; p2[wid] = s2; }
    __syncthreads();
    float S1 = p1[0] + p1[1] + p1[2] + p1[3];
    float S2 = p2[0] + p2[1] + p2[2] + p2[3];
    float mean = S1 * (1.f / 8192.f);
    float var  = S2 * (1.f / 8192.f) - mean * mean;
    float sc = gamma[n] * rsqrtf(fmaxf(var, 0.f) + 1e-5f);
    float sh = beta[n] - mean * sc;
#pragma unroll
    for (int b = 0; b < BB; b++) {
        float x1 = bf2f(x1b[((size_t)b * NN + n) * DOUT + t]);
        float g  = ws[OFF_G  + b * DOUT + t];
        float hb = ws[OFF_HB + b * DOUT + t];
        out[((size_t)b * NN + n) * DOUT + t] = (x1 + fmaxf(v[b] * sc + sh, 0.f)) * g + hb;
    }
}

extern "C" void kernel_launch(void* const* d_in, const int* in_sizes, int n_in,
                              void* d_out, int out_size, void* d_ws, size_t ws_size,
                              hipStream_t stream) {
    const float* ctx   = (const float*)d_in[0];
    const float* x     = (const float*)d_in[1];
    const float* Wl    = (const float*)d_in[2];
    const float* bl    = (const float*)d_in[3];
    const float* Whb   = (const float*)d_in[4];
    const float* Wg    = (const float*)d_in[5];
    const float* bg    = (const float*)d_in[6];
    const float* Wk    = (const float*)d_in[7];
    const float* Wv    = (const float*)d_in[8];
    const float* Wtc   = (const float*)d_in[9];
    const float* btc   = (const float*)d_in[10];
    const float* gamma = (const float*)d_in[11];
    const float* beta  = (const float*)d_in[12];
    float* out = (float*)d_out;
    float* ws  = (float*)d_ws;

    kXW     <<<44, 256, 0, stream>>>(Wl, Wtc, Wk, Wv, Wg, Whb, ws);
    kP      <<<BB, 1024, 0, stream>>>(ctx, bg, ws);
    k4m     <<<dim3(4, BB), 256, 0, stream>>>(ws);
    k5m     <<<dim3(2, BB), 256, 0, stream>>>(bl, btc, ws);
    k6_mfma <<<dim3(64, BB), 256, 0, stream>>>(x, bl, ws);
    k78     <<<NN, 256, 0, stream>>>(gamma, beta, out, ws);
}

// Round 7
// 239.826 us; speedup vs baseline: 2.0264x; 1.0808x over previous
//
#include <hip/hip_runtime.h>
#include <hip/hip_bf16.h>

#define BB   32
#define NN   2048
#define DIN  128
#define DOUT 256
#define DCTX 259

// ---- workspace layout (float-slot offsets) ----
#define OFF_TT   0u          // tt  bf16 [B][N][256] = 8388608 slots
#define OFF_AB   0u          // A  bf16 [B][256][256] (alias TT; dead before k6)
#define OFF_MTB  1048576u    // Mt bf16 [B][256][256] (alias TT; dead before k6)
#define OFF_X1B  8388608u    // x1 bf16 [B][N][256] = 8388608 slots
#define OFF_WMB  16777216u   // WM bf16 [B][256 e][128 i] = 524288
#define OFF_WLB  17301504u   // W_layer bf16 [256 o][128 i] = 16384
#define OFF_WLTB 17317888u   // W_layer^T bf16 [128 i][256 o] = 16384
#define OFF_WTCB 17334272u   // W_tc bf16 [256 e][256 o] = 32768
#define OFF_G    17367040u
#define OFF_HB   17375232u
#define OFF_TB   17383424u
#define OFF_WKT  17391616u   // [256 c][256 o] fp32
#define OFF_WVT  17457152u
#define OFF_WGT  17522688u   // [259 c][256 o]
#define OFF_WHT  17588992u
// end 17655296 slots = 70.6 MB

typedef short bf16x8 __attribute__((ext_vector_type(8)));
typedef float f32x4  __attribute__((ext_vector_type(4)));

static __device__ inline unsigned short f2bf(float f) {
    __hip_bfloat16 h = __float2bfloat16(f);
    return *(unsigned short*)&h;
}
static __device__ inline float bf2f(unsigned short u) {
    unsigned v = ((unsigned)u) << 16;
    float f;
    __builtin_memcpy(&f, &v, 4);
    return f;
}

// weight packing only: Wtc bf16, Wl/Wl^T bf16, Wk/Wv/Wg/Whb fp32 transposes. grid 44.
__global__ void kXW(const float* __restrict__ Wl, const float* __restrict__ Wtc,
                    const float* __restrict__ Wk, const float* __restrict__ Wv,
                    const float* __restrict__ Wg, const float* __restrict__ Whb,
                    float* __restrict__ ws) {
    unsigned bb = blockIdx.x, t = threadIdx.x;
    if (bb < 8u) {
        unsigned base = bb * 8192u;
        unsigned short* dst = (unsigned short*)(ws + OFF_WTCB);
#pragma unroll
        for (int j = 0; j < 32; j++) {
            unsigned i = base + (unsigned)j * 256u + t;
            dst[i] = f2bf(Wtc[i]);
        }
    } else if (bb == 8u) {
        unsigned short* dst = (unsigned short*)(ws + OFF_WLTB);   // [i][o]
        for (unsigned idx = t; idx < 32768u; idx += 256u) {
            unsigned i = idx >> 8, o = idx & 255u;
            dst[idx] = f2bf(Wl[o * 128u + i]);
        }
    } else if (bb == 9u) {
        unsigned short* dst = (unsigned short*)(ws + OFF_WLB);    // [o][i]
        for (unsigned idx = t; idx < 32768u; idx += 256u) dst[idx] = f2bf(Wl[idx]);
    } else {
        unsigned j = bb - 10u;
        const float* src; float* dst; unsigned C, c0;
        if (j < 8u)       { src = Wk;  dst = ws + OFF_WKT; C = 256; c0 = j * 32u; }
        else if (j < 16u) { src = Wv;  dst = ws + OFF_WVT; C = 256; c0 = (j - 8u) * 32u; }
        else if (j < 25u) { src = Wg;  dst = ws + OFF_WGT; C = 259; c0 = (j - 16u) * 32u; }
        else              { src = Whb; dst = ws + OFF_WHT; C = 259; c0 = (j - 25u) * 32u; }
        for (unsigned cc = c0; cc < c0 + 32u && cc < C; cc++)
            dst[cc * 256u + t] = src[t * C + cc];
    }
}

// Fused prep, 1024 threads: coalesced GEMVs + split softmax stats + A bf16. grid B.
__global__ __launch_bounds__(1024) void kP(const float* __restrict__ ctx,
                                           const float* __restrict__ bg,
                                           float* __restrict__ ws) {
    const int b = blockIdx.x, t = threadIdx.x;
    const int o = t & 255, q = t >> 8;
    __shared__ __align__(16) float cs[260];
    __shared__ __align__(16) float ks[256], vs[256], rms[256], ris[256];
    __shared__ float pm[1024], ps[1024];
    for (int i = t; i < DCTX; i += 1024) cs[i] = ctx[b * DCTX + i];
    __syncthreads();

    {
        const float* WT; int C;
        if (q == 0)      { WT = ws + OFF_WKT; C = 256; }
        else if (q == 1) { WT = ws + OFF_WVT; C = 256; }
        else if (q == 2) { WT = ws + OFF_WGT; C = DCTX; }
        else             { WT = ws + OFF_WHT; C = DCTX; }
        float s = 0.f;
#pragma unroll 8
        for (int c = 0; c < C; c++) s += WT[c * 256 + o] * cs[c];
        if (q == 0)      ks[o] = s;
        else if (q == 1) vs[o] = s;
        else if (q == 2) ws[OFF_G + b * DOUT + o] = 1.f / (1.f + __expf(-(s + bg[o])));
        else             ws[OFF_HB + b * DOUT + o] = s;
    }
    __syncthreads();

    const float ko = ks[o];
    const float4* vs4 = (const float4*)vs;
    float pmax = -1e30f;
#pragma unroll 4
    for (int j = q * 16; j < q * 16 + 16; j++) {
        float4 v = vs4[j];
        pmax = fmaxf(pmax, fmaxf(fmaxf(ko * v.x, ko * v.y), fmaxf(ko * v.z, ko * v.w)));
    }
    pm[q * 256 + o] = pmax;
    __syncthreads();
    float m = fmaxf(fmaxf(pm[o], pm[256 + o]), fmaxf(pm[512 + o], pm[768 + o]));
    float psum = 0.f;
#pragma unroll 4
    for (int j = q * 16; j < q * 16 + 16; j++) {
        float4 v = vs4[j];
        psum += __expf(ko * v.x - m) + __expf(ko * v.y - m)
              + __expf(ko * v.z - m) + __expf(ko * v.w - m);
    }
    ps[q * 256 + o] = psum;
    __syncthreads();
    float ri = 1.f / (ps[o] + ps[256 + o] + ps[512 + o] + ps[768 + o]);
    if (q == 0) { rms[o] = m; ris[o] = ri; }
    __syncthreads();

    const float ve = vs[o];
    float cp = 0.f;
#pragma unroll 4
    for (int o2 = q * 64; o2 < q * 64 + 64; o2++)
        cp += __expf(ks[o2] * ve - rms[o2]) * ris[o2];
    pm[q * 256 + o] = cp;
    __syncthreads();
    float ci = 1.f / (1e-9f + pm[o] + pm[256 + o] + pm[512 + o] + pm[768 + o]);
    unsigned short* Ab = (unsigned short*)(ws + OFF_AB) + (size_t)b * 65536u;
#pragma unroll 4
    for (int o2 = q * 64; o2 < q * 64 + 64; o2++) {
        float a = __expf(ks[o2] * ve - rms[o2]) * ris[o2] * ci;
        Ab[o2 * 256 + o] = f2bf(a);
    }
}

// Mt[e][o] = Wtc[e][o] - sum_o' Wtc[e][o'] * A[o][o']  (MFMA). grid (4 e-tiles, B).
__global__ __launch_bounds__(256) void k4m(float* __restrict__ ws) {
    const int t = threadIdx.x, wid = t >> 6, l = t & 63;
    const int b = blockIdx.y, et = blockIdx.x;
    const int lrow = l & 15, lk = l >> 4;
    const int rbase = et * 64 + (wid & 1) * 32;
    const int colbase = (wid >> 1) * 128;
    const unsigned short* Wtcb = (const unsigned short*)(ws + OFF_WTCB);
    const unsigned short* Ab = (const unsigned short*)(ws + OFF_AB) + (size_t)b * 65536u;

    f32x4 acc[2][8];
#pragma unroll
    for (int i = 0; i < 2; i++)
#pragma unroll
        for (int c = 0; c < 8; c++) acc[i][c] = (f32x4){0.f, 0.f, 0.f, 0.f};

    const unsigned short* ar0 = Wtcb + (rbase + lrow) * 256;
#pragma unroll
    for (int kk = 0; kk < 8; kk++) {
        int ko = kk * 32 + lk * 8;
        bf16x8 a0 = *(const bf16x8*)(ar0 + ko);
        bf16x8 a1 = *(const bf16x8*)(ar0 + 16 * 256 + ko);
        bf16x8 bfr[8];
#pragma unroll
        for (int c = 0; c < 8; c++)
            bfr[c] = *(const bf16x8*)(Ab + (colbase + c * 16 + lrow) * 256 + ko);
#pragma unroll
        for (int c = 0; c < 8; c++) {
            acc[0][c] = __builtin_amdgcn_mfma_f32_16x16x32_bf16(a0, bfr[c], acc[0][c], 0, 0, 0);
            acc[1][c] = __builtin_amdgcn_mfma_f32_16x16x32_bf16(a1, bfr[c], acc[1][c], 0, 0, 0);
        }
    }
    unsigned short* Mtb = (unsigned short*)(ws + OFF_MTB) + (size_t)b * 65536u;
#pragma unroll
    for (int t2 = 0; t2 < 2; t2++)
#pragma unroll
        for (int c = 0; c < 8; c++)
#pragma unroll
            for (int r = 0; r < 4; r++) {
                int row = rbase + t2 * 16 + lk * 4 + r;
                int col = colbase + c * 16 + lrow;
                float idv = bf2f(Wtcb[row * 256 + col]);
                Mtb[row * 256 + col] = f2bf(idv - acc[t2][c][r]);
            }
}

// WM[e][i] = sum_o Mt[e][o] * Wl^T[i][o]  (MFMA) + tbias. grid (2 e-tiles, B).
__global__ __launch_bounds__(256) void k5m(const float* __restrict__ bl,
                                           const float* __restrict__ btc,
                                           float* __restrict__ ws) {
    const int t = threadIdx.x, wid = t >> 6, l = t & 63;
    const int b = blockIdx.y, et = blockIdx.x;
    const int lrow = l & 15, lk = l >> 4;
    const int rbase = et * 128 + wid * 32;
    const unsigned short* Mtb = (const unsigned short*)(ws + OFF_MTB) + (size_t)b * 65536u;
    const unsigned short* Wltb = (const unsigned short*)(ws + OFF_WLTB);

    f32x4 acc[2][8];
#pragma unroll
    for (int i = 0; i < 2; i++)
#pragma unroll
        for (int c = 0; c < 8; c++) acc[i][c] = (f32x4){0.f, 0.f, 0.f, 0.f};

    const unsigned short* ar0 = Mtb + (rbase + lrow) * 256;
#pragma unroll
    for (int kk = 0; kk < 8; kk++) {
        int ko = kk * 32 + lk * 8;
        bf16x8 a0 = *(const bf16x8*)(ar0 + ko);
        bf16x8 a1 = *(const bf16x8*)(ar0 + 16 * 256 + ko);
        bf16x8 bfr[8];
#pragma unroll
        for (int c = 0; c < 8; c++)
            bfr[c] = *(const bf16x8*)(Wltb + (c * 16 + lrow) * 256 + ko);
#pragma unroll
        for (int c = 0; c < 8; c++) {
            acc[0][c] = __builtin_amdgcn_mfma_f32_16x16x32_bf16(a0, bfr[c], acc[0][c], 0, 0, 0);
            acc[1][c] = __builtin_amdgcn_mfma_f32_16x16x32_bf16(a1, bfr[c], acc[1][c], 0, 0, 0);
        }
    }
    unsigned short* WMBp = (unsigned short*)(ws + OFF_WMB) + (size_t)b * 32768u;
#pragma unroll
    for (int t2 = 0; t2 < 2; t2++)
#pragma unroll
        for (int c = 0; c < 8; c++)
#pragma unroll
            for (int r = 0; r < 4; r++) {
                int row = rbase + t2 * 16 + lk * 4 + r;
                int col = c * 16 + lrow;
                WMBp[row * 128 + col] = f2bf(acc[t2][c][r]);
            }
    if (t < 128) {
        int e = et * 128 + t;
        const unsigned short* mrow = Mtb + e * 256;
        float s = 0.f;
#pragma unroll 8
        for (int o = 0; o < 256; o++) s += bl[o] * bf2f(mrow[o]);
        ws[OFF_TB + b * DOUT + e] = s + btc[e];
    }
}

// dual GEMM: 64-row block; x fp32 staged once -> bf16 LDS tile (padded, 2-way-free
// ds_read_b128 a-frags); each wave: 2 tensor passes x 4x4 16x16 tiles.
// grid (32, B), 256 threads. MFMA:VMEM = 16:4 per k-step.
#define LDP 136   // LDS row stride in shorts (128 + 8): a-frag reads 2-way conflict only
__global__ __launch_bounds__(256) void k6_mfma(const float* __restrict__ x,
                                               const float* __restrict__ bl,
                                               float* __restrict__ ws) {
    const int t = threadIdx.x;
    const int wid = t >> 6, l = t & 63;
    const int b = blockIdx.y;
    const int n0 = blockIdx.x * 64;
    const int lrow = l & 15, lk = l >> 4;
    __shared__ unsigned short xs[64 * LDP];

    // stage x tile (64 rows x 128 k) fp32 -> bf16 LDS, fully coalesced 16B loads
    const float4* xg = (const float4*)(x + (size_t)(b * NN + n0) * DIN);
#pragma unroll
    for (int it = 0; it < 8; it++) {
        int idx = it * 256 + t;
        int row = idx >> 5, kq = idx & 31;       // kq = float4 index within row
        float4 v = xg[idx];
        ushort4 u;
        u.x = f2bf(v.x); u.y = f2bf(v.y); u.z = f2bf(v.z); u.w = f2bf(v.w);
        *(ushort4*)(xs + row * LDP + kq * 4) = u;
    }
    __syncthreads();

    unsigned short* x1p = (unsigned short*)(ws + OFF_X1B);
    unsigned short* ttp = (unsigned short*)(ws + OFF_TT);
    const int colbase = wid * 64;

#pragma unroll
    for (int tc = 0; tc < 2; tc++) {
        const unsigned short* wb = (tc == 0)
            ? (const unsigned short*)(ws + OFF_WLB)
            : (const unsigned short*)(ws + OFF_WMB) + (size_t)b * 32768u;
        float bias[4];
#pragma unroll
        for (int ct = 0; ct < 4; ct++) {
            int col = colbase + ct * 16 + lrow;
            bias[ct] = (tc == 0) ? bl[col] : ws[OFF_TB + b * DOUT + col];
        }
        f32x4 acc[4][4];
#pragma unroll
        for (int rt = 0; rt < 4; rt++)
#pragma unroll
            for (int ct = 0; ct < 4; ct++) acc[rt][ct] = (f32x4){0.f, 0.f, 0.f, 0.f};

#pragma unroll
        for (int kk = 0; kk < 4; kk++) {
            int ko = kk * 32 + lk * 8;
            bf16x8 a[4];
#pragma unroll
            for (int rt = 0; rt < 4; rt++)
                a[rt] = *(const bf16x8*)(xs + (rt * 16 + lrow) * LDP + ko);
            bf16x8 bf[4];
#pragma unroll
            for (int ct = 0; ct < 4; ct++)
                bf[ct] = *(const bf16x8*)(wb + (size_t)(colbase + ct * 16 + lrow) * DIN + ko);
#pragma unroll
            for (int rt = 0; rt < 4; rt++)
#pragma unroll
                for (int ct = 0; ct < 4; ct++)
                    acc[rt][ct] = __builtin_amdgcn_mfma_f32_16x16x32_bf16(a[rt], bf[ct], acc[rt][ct], 0, 0, 0);
        }
        unsigned short* dst = (tc == 0) ? x1p : ttp;
#pragma unroll
        for (int rt = 0; rt < 4; rt++)
#pragma unroll
            for (int ct = 0; ct < 4; ct++)
#pragma unroll
                for (int r = 0; r < 4; r++) {
                    int row = n0 + rt * 16 + lk * 4 + r;
                    int col = colbase + ct * 16 + lrow;
                    dst[(size_t)((b * NN + row) * DOUT) + col] = f2bf(acc[rt][ct][r] + bias[ct]);
                }
    }
}

// fused BN stats + epilogue, 1024 threads: thread (q,o) owns 8 batches. grid N.
__global__ __launch_bounds__(1024) void k78(const float* __restrict__ gamma,
                                            const float* __restrict__ beta,
                                            float* __restrict__ out,
                                            float* __restrict__ ws) {
    const int n = blockIdx.x, t = threadIdx.x;
    const int o = t & 255, q = t >> 8;
    const int wid = t >> 6, l = t & 63;
    const unsigned short* ttb = (const unsigned short*)(ws + OFF_TT);
    const unsigned short* x1b = (const unsigned short*)(ws + OFF_X1B);
    float v[8];
    float s1 = 0.f, s2 = 0.f;
#pragma unroll
    for (int j = 0; j < 8; j++) {
        int b = q * 8 + j;
        float vv = bf2f(ttb[((size_t)b * NN + n) * DOUT + o]);
        v[j] = vv; s1 += vv; s2 += vv * vv;
    }
#pragma unroll
    for (int off = 32; off > 0; off >>= 1) {
        s1 += __shfl_xor(s1, off, 64);
        s2 += __shfl_xor(s2, off, 64);
    }
    __shared__ float p1[16], p2[16];
    if (l == 0) { p1[wid] = s1; p2[wid] = s2; }
    __syncthreads();
    float S1 = 0.f, S2 = 0.f;
#pragma unroll
    for (int w = 0; w < 16; w++) { S1 += p1[w]; S2 += p2[w]; }
    float mean = S1 * (1.f / 8192.f);
    float var  = S2 * (1.f / 8192.f) - mean * mean;
    float sc = gamma[n] * rsqrtf(fmaxf(var, 0.f) + 1e-5f);
    float sh = beta[n] - mean * sc;
#pragma unroll
    for (int j = 0; j < 8; j++) {
        int b = q * 8 + j;
        float x1 = bf2f(x1b[((size_t)b * NN + n) * DOUT + o]);
        float g  = ws[OFF_G  + b * DOUT + o];
        float hb = ws[OFF_HB + b * DOUT + o];
        out[((size_t)b * NN + n) * DOUT + o] = (x1 + fmaxf(v[j] * sc + sh, 0.f)) * g + hb;
    }
}

extern "C" void kernel_launch(void* const* d_in, const int* in_sizes, int n_in,
                              void* d_out, int out_size, void* d_ws, size_t ws_size,
                              hipStream_t stream) {
    const float* ctx   = (const float*)d_in[0];
    const float* x     = (const float*)d_in[1];
    const float* Wl    = (const float*)d_in[2];
    const float* bl    = (const float*)d_in[3];
    const float* Whb   = (const float*)d_in[4];
    const float* Wg    = (const float*)d_in[5];
    const float* bg    = (const float*)d_in[6];
    const float* Wk    = (const float*)d_in[7];
    const float* Wv    = (const float*)d_in[8];
    const float* Wtc   = (const float*)d_in[9];
    const float* btc   = (const float*)d_in[10];
    const float* gamma = (const float*)d_in[11];
    const float* beta  = (const float*)d_in[12];
    float* out = (float*)d_out;
    float* ws  = (float*)d_ws;

    kXW     <<<44, 256, 0, stream>>>(Wl, Wtc, Wk, Wv, Wg, Whb, ws);
    kP      <<<BB, 1024, 0, stream>>>(ctx, bg, ws);
    k4m     <<<dim3(4, BB), 256, 0, stream>>>(ws);
    k5m     <<<dim3(2, BB), 256, 0, stream>>>(bl, btc, ws);
    k6_mfma <<<dim3(32, BB), 256, 0, stream>>>(x, bl, ws);
    k78     <<<NN, 1024, 0, stream>>>(gamma, beta, out, ws);
}